// Round 9
// baseline (193.503 us; speedup 1.0000x reference)
//
#include <hip/hip_runtime.h>
#include <hip/hip_bf16.h>
#include <math.h>

#define IN_DIM 256
#define OUT_DIM 128
#define LEAKY 0.2f

typedef __attribute__((ext_vector_type(8))) short bf16x8;
typedef __attribute__((ext_vector_type(4))) float f32x4;

__device__ __forceinline__ unsigned short f2bf(float f) {
    union { float f; unsigned int u; } v; v.f = f;
    unsigned int r = v.u + 0x7FFFu + ((v.u >> 16) & 1u);
    return (unsigned short)(r >> 16);
}
__device__ __forceinline__ float bf2f(unsigned int hi16) {
    union { unsigned int u; float f; } v; v.u = hi16 << 16;
    return v.f;
}

// ---------------- wcomb[0:256] = W_src @ a[0:128]
__global__ __launch_bounds__(256) void combine_w_kernel(
    const float* __restrict__ W_src, const float* __restrict__ a,
    float* __restrict__ wcomb) {
    int i = blockIdx.x * blockDim.x + threadIdx.x;
    if (i < 256) {
        float s = 0.f;
        #pragma unroll 4
        for (int k = 0; k < OUT_DIM; ++k) s += W_src[i * OUT_DIM + k] * a[k];
        wcomb[i] = s;
    }
}

// ---------------- pre-swizzle W_tgt into bf16 fragment-major
__global__ __launch_bounds__(256) void wswz_kernel(
    const float* __restrict__ W, unsigned short* __restrict__ Wswz) {
    int idx = blockIdx.x * 256 + threadIdx.x;   // 0..4095
    if (idx >= 4096) return;
    int l  = idx & 63;
    int fj = (idx >> 6) & 7;
    int kc = idx >> 9;
    int col = fj * 16 + (l & 15);
    int kb  = kc * 32 + (l >> 4) * 8;
    unsigned int u[4];
    #pragma unroll
    for (int p = 0; p < 4; ++p) {
        unsigned short e0 = f2bf(W[(size_t)(kb + 2 * p + 0) * OUT_DIM + col]);
        unsigned short e1 = f2bf(W[(size_t)(kb + 2 * p + 1) * OUT_DIM + col]);
        u[p] = (unsigned int)e0 | ((unsigned int)e1 << 16);
    }
    *(uint4*)(Wswz + (size_t)idx * 8) = make_uint4(u[0], u[1], u[2], u[3]);
}

// ---------------- FUSED: score_i GEMV (7/8 of blocks) + hist/rank (1/8 of blocks)
// Interleaved so the atomic-latency hist work hides under the BW-bound gemv.
__global__ __launch_bounds__(256) void gemv_hist_kernel(
    const float* __restrict__ X, const float* __restrict__ w,
    float* __restrict__ score, int M,
    const int* __restrict__ src_id, int* __restrict__ counts,
    int* __restrict__ rank, int E) {
    int bid = blockIdx.x;
    int grp = bid >> 3;
    if ((bid & 7) == 7) {
        // ---- hist branch: 256 edges per block
        int e = grp * 256 + threadIdx.x;
        if (e < E) rank[e] = atomicAdd(&counts[src_id[e]], 1);
        return;
    }
    // ---- gemv branch: 4 rows per block (wave per row)
    int gemv_id = bid - grp;
    int wid = gemv_id * 4 + (threadIdx.x >> 6);
    int lane = threadIdx.x & 63;
    if (wid >= M) return;
    const float4* row = (const float4*)(X + (size_t)wid * IN_DIM);
    float4 x = row[lane];
    float4 wv = ((const float4*)w)[lane];
    float s = x.x * wv.x + x.y * wv.y + x.z * wv.z + x.w * wv.w;
    #pragma unroll
    for (int d = 1; d < 64; d <<= 1) s += __shfl_xor(s, d);
    if (lane == 0) score[wid] = s;
}

// ---------------- MFMA GEMM: single-phase full-K staging (32 KB LDS, 1 barrier)
__global__ __launch_bounds__(256) void gemm_mfma_kernel(
    const float* __restrict__ A,            // [M,256] f32
    const unsigned short* __restrict__ Wswz,// fragment-major bf16
    const float* __restrict__ a_hi,         // [128]
    unsigned short* __restrict__ Hb,        // [M,128] bf16
    float* __restrict__ score, int M) {
    __shared__ unsigned short As[64 * 256];  // 32 KB, XOR-swizzled
    int tid = threadIdx.x;
    int w = tid >> 6;
    int l = tid & 63;
    int bm = blockIdx.x * 64;

    int srow = tid >> 4;
    int kcol = (tid & 15) * 4;

    float aw[8];
    #pragma unroll
    for (int j = 0; j < 8; ++j) aw[j] = a_hi[j * 16 + (l & 15)];

    f32x4 acc[8];
    f32x4 zero = {0.f, 0.f, 0.f, 0.f};
    #pragma unroll
    for (int j = 0; j < 8; ++j) acc[j] = zero;

    float4 pre[16];
    #pragma unroll
    for (int p = 0; p < 4; ++p) {
        int grow = bm + srow + p * 16;
        const float* rp = A + (size_t)(grow < M ? grow : M - 1) * IN_DIM;
        bool ok = grow < M;
        #pragma unroll
        for (int c = 0; c < 4; ++c) {
            float4 v = *(const float4*)(rp + c * 64 + kcol);
            pre[p * 4 + c] = ok ? v : make_float4(0.f, 0.f, 0.f, 0.f);
        }
    }
    #pragma unroll
    for (int p = 0; p < 4; ++p) {
        int row = srow + p * 16;
        #pragma unroll
        for (int c = 0; c < 4; ++c) {
            float4 v = pre[p * 4 + c];
            unsigned int b0 = (unsigned int)f2bf(v.x) | ((unsigned int)f2bf(v.y) << 16);
            unsigned int b1 = (unsigned int)f2bf(v.z) | ((unsigned int)f2bf(v.w) << 16);
            unsigned int byteoff =
                (unsigned int)(row * 512 + (c * 64 + kcol) * 2) ^ ((row & 7) << 4);
            *(uint2*)((char*)As + byteoff) = make_uint2(b0, b1);
        }
    }
    __syncthreads();

    #pragma unroll
    for (int kc = 0; kc < 8; ++kc) {
        int row = w * 16 + (l & 15);
        unsigned int byteoff =
            (unsigned int)(row * 512 + kc * 64 + (l >> 4) * 16) ^ ((row & 7) << 4);
        bf16x8 af = *(const bf16x8*)((const char*)As + byteoff);
        #pragma unroll
        for (int j = 0; j < 8; ++j) {
            bf16x8 bfj = *(const bf16x8*)(Wswz + ((size_t)(kc * 8 + j) * 64 + l) * 8);
            acc[j] = __builtin_amdgcn_mfma_f32_16x16x32_bf16(af, bfj, acc[j], 0, 0, 0);
        }
    }
    #pragma unroll
    for (int r = 0; r < 4; ++r) {
        int row = bm + w * 16 + (l >> 4) * 4 + r;
        if (row < M) {
            float s = 0.f;
            #pragma unroll
            for (int j = 0; j < 8; ++j) {
                float v = acc[j][r];
                Hb[(size_t)row * OUT_DIM + j * 16 + (l & 15)] = f2bf(v);
                s += v * aw[j];
            }
            s += __shfl_xor(s, 1); s += __shfl_xor(s, 2);
            s += __shfl_xor(s, 4); s += __shfl_xor(s, 8);
            if ((l & 15) == 0) score[row] = s;
        }
    }
}

// ---------------- 2-level exclusive scan
__global__ __launch_bounds__(256) void scan1_kernel(
    const int* __restrict__ counts, int* __restrict__ offs,
    int* __restrict__ blockSums, int n) {
    __shared__ int sd[256];
    int b = blockIdx.x, tid = threadIdx.x;
    int base = b * 1024 + tid * 4;
    int v0 = base + 0 < n ? counts[base + 0] : 0;
    int v1 = base + 1 < n ? counts[base + 1] : 0;
    int v2 = base + 2 < n ? counts[base + 2] : 0;
    int v3 = base + 3 < n ? counts[base + 3] : 0;
    int p1 = v0, p2 = v0 + v1, p3 = v0 + v1 + v2;
    int tsum = p3 + v3;
    sd[tid] = tsum;
    __syncthreads();
    #pragma unroll
    for (int off = 1; off < 256; off <<= 1) {
        int t = tid >= off ? sd[tid - off] : 0;
        __syncthreads();
        sd[tid] += t;
        __syncthreads();
    }
    int ex = sd[tid] - tsum;
    if (base + 0 < n) offs[base + 0] = ex;
    if (base + 1 < n) offs[base + 1] = ex + p1;
    if (base + 2 < n) offs[base + 2] = ex + p2;
    if (base + 3 < n) offs[base + 3] = ex + p3;
    if (tid == 255) blockSums[b] = sd[255];
}

__global__ __launch_bounds__(256) void scan2_kernel(
    const int* __restrict__ blockSums, int* __restrict__ blockOffs, int nb) {
    __shared__ int sd[256];
    int tid = threadIdx.x;
    int v = tid < nb ? blockSums[tid] : 0;
    sd[tid] = v;
    __syncthreads();
    #pragma unroll
    for (int off = 1; off < 256; off <<= 1) {
        int t = tid >= off ? sd[tid - off] : 0;
        __syncthreads();
        sd[tid] += t;
        __syncthreads();
    }
    blockOffs[tid] = sd[tid] - v;
}

__global__ __launch_bounds__(256) void scan3_kernel(
    int* __restrict__ offs, const int* __restrict__ blockOffs, int n, int E) {
    int i = blockIdx.x * blockDim.x + threadIdx.x;
    if (i < n) offs[i] += blockOffs[i >> 10];
    if (i == 0) offs[n] = E;
}

// ---------------- fused scatter, zero atomics: p = offs[s] + rank[e], packed 8B write
__global__ __launch_bounds__(256) void scatter_fused_kernel(
    const int* __restrict__ src_id, const int* __restrict__ tgt_id,
    const float* __restrict__ score_i, const float* __restrict__ score_j,
    const int* __restrict__ offs, const int* __restrict__ rank,
    uint2* __restrict__ pairs, int E) {
    int e = blockIdx.x * blockDim.x + threadIdx.x;
    if (e >= E) return;
    int s = src_id[e], t = tgt_id[e];
    float x = score_i[s] + score_j[t];
    x = x > 0.f ? x : LEAKY * x;
    x = fminf(30.f, fmaxf(-30.f, x));
    float ex = expf(x);
    int p = offs[s] + rank[e];
    pairs[p] = make_uint2((unsigned int)t, __float_as_uint(ex));
}

// ---------------- aggregate: wave per node, 8 edges in flight, inline denom, fused ELU
// 8 groups x 8 lanes; lane (g, cl) owns cols cl*16..cl*16+15 for edges e ≡ g (mod 8).
__global__ __launch_bounds__(256) void agg_kernel(
    const uint2* __restrict__ pairs, const int* __restrict__ offs,
    const unsigned short* __restrict__ hjb, float* __restrict__ out, int N) {
    int node = (int)((blockIdx.x * (long long)blockDim.x + threadIdx.x) >> 6);
    if (node >= N) return;
    int lane = threadIdx.x & 63;
    int g  = lane >> 3;   // 0..7 edge group
    int cl = lane & 7;    // 0..7 column lane
    int beg = offs[node], end = offs[node + 1];
    int deg = end - beg;
    float den = 0.f;
    float acc[16];
    #pragma unroll
    for (int i = 0; i < 16; ++i) acc[i] = 0.f;

    int iters = (deg + 7) >> 3;               // uniform across the wave
    for (int it = 0; it < iters; ++it) {
        int e = g + 8 * it;
        bool valid = e < deg;
        int idx = beg + (valid ? e : 0);
        uint2 tw = pairs[idx];                // same addr within 8-lane group -> broadcast
        int t = (int)tw.x;
        float wgt = valid ? __uint_as_float(tw.y) : 0.f;
        den += wgt;
        const unsigned short* hp = hjb + (size_t)t * OUT_DIM + cl * 16;
        uint4 u0 = *(const uint4*)(hp);
        uint4 u1 = *(const uint4*)(hp + 8);
        acc[0]  += bf2f(u0.x & 0xffffu) * wgt;  acc[1]  += bf2f(u0.x >> 16) * wgt;
        acc[2]  += bf2f(u0.y & 0xffffu) * wgt;  acc[3]  += bf2f(u0.y >> 16) * wgt;
        acc[4]  += bf2f(u0.z & 0xffffu) * wgt;  acc[5]  += bf2f(u0.z >> 16) * wgt;
        acc[6]  += bf2f(u0.w & 0xffffu) * wgt;  acc[7]  += bf2f(u0.w >> 16) * wgt;
        acc[8]  += bf2f(u1.x & 0xffffu) * wgt;  acc[9]  += bf2f(u1.x >> 16) * wgt;
        acc[10] += bf2f(u1.y & 0xffffu) * wgt;  acc[11] += bf2f(u1.y >> 16) * wgt;
        acc[12] += bf2f(u1.z & 0xffffu) * wgt;  acc[13] += bf2f(u1.z >> 16) * wgt;
        acc[14] += bf2f(u1.w & 0xffffu) * wgt;  acc[15] += bf2f(u1.w >> 16) * wgt;
    }
    // reduce across the 8 groups (lane bits 3..5); within-group lanes hold distinct cols
    den += __shfl_xor(den, 8);
    den += __shfl_xor(den, 16);
    den += __shfl_xor(den, 32);
    float inv = 1.f / (den + 1e-8f);
    #pragma unroll
    for (int i = 0; i < 16; ++i) {
        acc[i] += __shfl_xor(acc[i], 8);
        acc[i] += __shfl_xor(acc[i], 16);
        acc[i] += __shfl_xor(acc[i], 32);
        acc[i] *= inv;
        acc[i] = acc[i] > 0.f ? acc[i] : expm1f(acc[i]);
    }
    if (lane < 8) {
        float* op = out + (size_t)node * OUT_DIM + cl * 16;
        *(float4*)(op + 0)  = make_float4(acc[0],  acc[1],  acc[2],  acc[3]);
        *(float4*)(op + 4)  = make_float4(acc[4],  acc[5],  acc[6],  acc[7]);
        *(float4*)(op + 8)  = make_float4(acc[8],  acc[9],  acc[10], acc[11]);
        *(float4*)(op + 12) = make_float4(acc[12], acc[13], acc[14], acc[15]);
    }
}

// ---------------- fallback path (atomic scatter) if ws too small
__global__ __launch_bounds__(256) void edge_pass1_kernel(
    const int* __restrict__ src_id, const int* __restrict__ tgt_id,
    const float* __restrict__ score_i, const float* __restrict__ score_j,
    float* __restrict__ exp_e, float* __restrict__ denom, int E) {
    int e = blockIdx.x * blockDim.x + threadIdx.x;
    if (e >= E) return;
    int s = src_id[e], t = tgt_id[e];
    float x = score_i[s] + score_j[t];
    x = x > 0.f ? x : LEAKY * x;
    x = fminf(30.f, fmaxf(-30.f, x));
    float ex = expf(x);
    exp_e[e] = ex;
    atomicAdd(&denom[s], ex);
}

__global__ __launch_bounds__(256) void edge_pass2_kernel(
    const int* __restrict__ src_id, const int* __restrict__ tgt_id,
    const unsigned short* __restrict__ hjb, const float* __restrict__ exp_e,
    const float* __restrict__ denom, float* __restrict__ out, int E) {
    int idx = blockIdx.x * blockDim.x + threadIdx.x;
    int e = idx >> 6;
    if (e >= E) return;
    int lane = idx & 63;
    int s = src_id[e], t = tgt_id[e];
    float alpha = exp_e[e] / (denom[s] + 1e-8f);
    unsigned int u = *(const unsigned int*)(hjb + (size_t)t * OUT_DIM + lane * 2);
    atomicAdd(out + (size_t)s * OUT_DIM + lane * 2 + 0, bf2f(u & 0xffffu) * alpha);
    atomicAdd(out + (size_t)s * OUT_DIM + lane * 2 + 1, bf2f(u >> 16) * alpha);
}

__global__ __launch_bounds__(256) void elu_kernel(float* __restrict__ out, int n4) {
    int i = blockIdx.x * blockDim.x + threadIdx.x;
    if (i >= n4) return;
    float4 v = ((float4*)out)[i];
    v.x = v.x > 0.f ? v.x : expm1f(v.x);
    v.y = v.y > 0.f ? v.y : expm1f(v.y);
    v.z = v.z > 0.f ? v.z : expm1f(v.z);
    v.w = v.w > 0.f ? v.w : expm1f(v.w);
    ((float4*)out)[i] = v;
}

extern "C" void kernel_launch(void* const* d_in, const int* in_sizes, int n_in,
                              void* d_out, int out_size, void* d_ws, size_t ws_size,
                              hipStream_t stream) {
    const float* src   = (const float*)d_in[0];
    const float* tgt   = (const float*)d_in[1];
    const float* W_src = (const float*)d_in[2];
    const float* W_tgt = (const float*)d_in[3];
    const float* a     = (const float*)d_in[4];
    const int*   edge  = (const int*)d_in[5];

    int N_src = in_sizes[0] / IN_DIM;
    int N_tgt = in_sizes[1] / IN_DIM;
    int E     = in_sizes[5] / 2;
    const int* src_id = edge;
    const int* tgt_id = edge + E;

    float* out = (float*)d_out;

    char* ws = (char*)d_ws;
    size_t off = 0;
    auto alloc = [&](size_t bytes) {
        void* p = ws + off;
        off += (bytes + 255) & ~(size_t)255;
        return p;
    };

    unsigned short* hjb  = (unsigned short*)alloc((size_t)N_tgt * OUT_DIM * 2);
    float* score_i = (float*)alloc((size_t)N_src * 4);
    float* score_j = (float*)alloc((size_t)N_tgt * 4);
    float* wcomb   = (float*)alloc(256 * 4);
    unsigned short* Wswz = (unsigned short*)alloc(4096 * 8 * 2);
    int*   counts    = (int*)alloc((size_t)N_src * 4);
    int*   offs      = (int*)alloc((size_t)(N_src + 1) * 4);
    int*   blockSums = (int*)alloc(256 * 4);
    int*   blockOffs = (int*)alloc(256 * 4);
    float* denom     = (float*)alloc((size_t)N_src * 4);   // fallback only
    float* exp_e     = (float*)alloc((size_t)E * 4);       // fallback only
    size_t fb_need = off;
    int*   rank      = (int*)alloc((size_t)E * 4);
    uint2* pairs     = (uint2*)alloc((size_t)E * 8);
    size_t csr_need = off;
    (void)fb_need;

    bool use_csr = (ws_size >= csr_need);

    combine_w_kernel<<<1, 256, 0, stream>>>(W_src, a, wcomb);
    wswz_kernel<<<16, 256, 0, stream>>>(W_tgt, Wswz);

    if (use_csr) {
        hipMemsetAsync(counts, 0, (size_t)N_src * sizeof(int), stream);
        // fused gemv(score_i) + hist/rank, interleaved 7:1
        int gemvBlocks = (N_src + 3) / 4;
        int histBlocks = (E + 255) / 256;
        int g7 = (gemvBlocks + 6) / 7;
        int T = 8 * (histBlocks > g7 ? histBlocks : g7);
        gemv_hist_kernel<<<T, 256, 0, stream>>>(
            src, wcomb, score_i, N_src, src_id, counts, rank, E);
        gemm_mfma_kernel<<<(N_tgt + 63) / 64, 256, 0, stream>>>(
            tgt, Wswz, a + OUT_DIM, hjb, score_j, N_tgt);
        int nb = (N_src + 1023) / 1024;
        scan1_kernel<<<nb, 256, 0, stream>>>(counts, offs, blockSums, N_src);
        scan2_kernel<<<1, 256, 0, stream>>>(blockSums, blockOffs, nb);
        scan3_kernel<<<(N_src + 255) / 256, 256, 0, stream>>>(offs, blockOffs, N_src, E);
        scatter_fused_kernel<<<(E + 255) / 256, 256, 0, stream>>>(
            src_id, tgt_id, score_i, score_j, offs, rank, pairs, E);
        agg_kernel<<<(N_src + 3) / 4, 256, 0, stream>>>(
            pairs, offs, hjb, out, N_src);
    } else {
        int gemvBlocks = (N_src + 3) / 4;
        gemv_hist_kernel<<<8 * ((gemvBlocks + 6) / 7), 256, 0, stream>>>(
            src, wcomb, score_i, N_src, src_id, counts, rank, 0);
        gemm_mfma_kernel<<<(N_tgt + 63) / 64, 256, 0, stream>>>(
            tgt, Wswz, a + OUT_DIM, hjb, score_j, N_tgt);
        hipMemsetAsync(out, 0, (size_t)N_src * OUT_DIM * sizeof(float), stream);
        hipMemsetAsync(denom, 0, (size_t)N_src * sizeof(float), stream);
        edge_pass1_kernel<<<(E + 255) / 256, 256, 0, stream>>>(
            src_id, tgt_id, score_i, score_j, exp_e, denom, E);
        edge_pass2_kernel<<<(int)(((long long)E * 64 + 255) / 256), 256, 0, stream>>>(
            src_id, tgt_id, hjb, exp_e, denom, out, E);
        elu_kernel<<<(N_src * OUT_DIM / 4 + 255) / 256, 256, 0, stream>>>(
            out, N_src * OUT_DIM / 4);
    }
}

// Round 10
// 172.378 us; speedup vs baseline: 1.1226x; 1.1226x over previous
//
#include <hip/hip_runtime.h>
#include <hip/hip_bf16.h>
#include <math.h>

#define IN_DIM 256
#define OUT_DIM 128
#define LEAKY 0.2f

typedef __attribute__((ext_vector_type(8))) short bf16x8;
typedef __attribute__((ext_vector_type(4))) float f32x4;

__device__ __forceinline__ unsigned short f2bf(float f) {
    union { float f; unsigned int u; } v; v.f = f;
    unsigned int r = v.u + 0x7FFFu + ((v.u >> 16) & 1u);
    return (unsigned short)(r >> 16);
}
__device__ __forceinline__ float bf2f(unsigned int hi16) {
    union { unsigned int u; float f; } v; v.u = hi16 << 16;
    return v.f;
}

// ---------------- prep: blocks 0..15 = wswz (W_tgt -> bf16 fragment-major),
//                  block 16 = wcomb[0:256] = W_src @ a[0:128]
__global__ __launch_bounds__(256) void prep_kernel(
    const float* __restrict__ W_src, const float* __restrict__ W_tgt,
    const float* __restrict__ a, float* __restrict__ wcomb,
    unsigned short* __restrict__ Wswz) {
    if (blockIdx.x == 16) {
        int i = threadIdx.x;
        float s = 0.f;
        #pragma unroll 4
        for (int k = 0; k < OUT_DIM; ++k) s += W_src[i * OUT_DIM + k] * a[k];
        wcomb[i] = s;
        return;
    }
    int idx = blockIdx.x * 256 + threadIdx.x;   // 0..4095
    int l  = idx & 63;
    int fj = (idx >> 6) & 7;
    int kc = idx >> 9;
    int col = fj * 16 + (l & 15);
    int kb  = kc * 32 + (l >> 4) * 8;
    unsigned int u[4];
    #pragma unroll
    for (int p = 0; p < 4; ++p) {
        unsigned short e0 = f2bf(W_tgt[(size_t)(kb + 2 * p + 0) * OUT_DIM + col]);
        unsigned short e1 = f2bf(W_tgt[(size_t)(kb + 2 * p + 1) * OUT_DIM + col]);
        u[p] = (unsigned int)e0 | ((unsigned int)e1 << 16);
    }
    *(uint4*)(Wswz + (size_t)idx * 8) = make_uint4(u[0], u[1], u[2], u[3]);
}

// ---------------- FUSED: score_i GEMV (7/8 of blocks) + hist/rank (1/8 of blocks)
__global__ __launch_bounds__(256) void gemv_hist_kernel(
    const float* __restrict__ X, const float* __restrict__ w,
    float* __restrict__ score, int M,
    const int* __restrict__ src_id, int* __restrict__ counts,
    int* __restrict__ rank, int E) {
    int bid = blockIdx.x;
    int grp = bid >> 3;
    if ((bid & 7) == 7) {
        int e = grp * 256 + threadIdx.x;
        if (e < E) rank[e] = atomicAdd(&counts[src_id[e]], 1);
        return;
    }
    int gemv_id = bid - grp;
    int wid = gemv_id * 4 + (threadIdx.x >> 6);
    int lane = threadIdx.x & 63;
    if (wid >= M) return;
    const float4* row = (const float4*)(X + (size_t)wid * IN_DIM);
    float4 x = row[lane];
    float4 wv = ((const float4*)w)[lane];
    float s = x.x * wv.x + x.y * wv.y + x.z * wv.z + x.w * wv.w;
    #pragma unroll
    for (int d = 1; d < 64; d <<= 1) s += __shfl_xor(s, d);
    if (lane == 0) score[wid] = s;
}

// ---------------- MFMA GEMM: single-phase full-K staging (32 KB LDS, 1 barrier)
__global__ __launch_bounds__(256) void gemm_mfma_kernel(
    const float* __restrict__ A,            // [M,256] f32
    const unsigned short* __restrict__ Wswz,// fragment-major bf16
    const float* __restrict__ a_hi,         // [128]
    unsigned short* __restrict__ Hb,        // [M,128] bf16
    float* __restrict__ score, int M) {
    __shared__ unsigned short As[64 * 256];  // 32 KB, XOR-swizzled
    int tid = threadIdx.x;
    int w = tid >> 6;
    int l = tid & 63;
    int bm = blockIdx.x * 64;

    int srow = tid >> 4;
    int kcol = (tid & 15) * 4;

    float aw[8];
    #pragma unroll
    for (int j = 0; j < 8; ++j) aw[j] = a_hi[j * 16 + (l & 15)];

    f32x4 acc[8];
    f32x4 zero = {0.f, 0.f, 0.f, 0.f};
    #pragma unroll
    for (int j = 0; j < 8; ++j) acc[j] = zero;

    float4 pre[16];
    #pragma unroll
    for (int p = 0; p < 4; ++p) {
        int grow = bm + srow + p * 16;
        const float* rp = A + (size_t)(grow < M ? grow : M - 1) * IN_DIM;
        bool ok = grow < M;
        #pragma unroll
        for (int c = 0; c < 4; ++c) {
            float4 v = *(const float4*)(rp + c * 64 + kcol);
            pre[p * 4 + c] = ok ? v : make_float4(0.f, 0.f, 0.f, 0.f);
        }
    }
    #pragma unroll
    for (int p = 0; p < 4; ++p) {
        int row = srow + p * 16;
        #pragma unroll
        for (int c = 0; c < 4; ++c) {
            float4 v = pre[p * 4 + c];
            unsigned int b0 = (unsigned int)f2bf(v.x) | ((unsigned int)f2bf(v.y) << 16);
            unsigned int b1 = (unsigned int)f2bf(v.z) | ((unsigned int)f2bf(v.w) << 16);
            unsigned int byteoff =
                (unsigned int)(row * 512 + (c * 64 + kcol) * 2) ^ ((row & 7) << 4);
            *(uint2*)((char*)As + byteoff) = make_uint2(b0, b1);
        }
    }
    __syncthreads();

    #pragma unroll
    for (int kc = 0; kc < 8; ++kc) {
        int row = w * 16 + (l & 15);
        unsigned int byteoff =
            (unsigned int)(row * 512 + kc * 64 + (l >> 4) * 16) ^ ((row & 7) << 4);
        bf16x8 af = *(const bf16x8*)((const char*)As + byteoff);
        #pragma unroll
        for (int j = 0; j < 8; ++j) {
            bf16x8 bfj = *(const bf16x8*)(Wswz + ((size_t)(kc * 8 + j) * 64 + l) * 8);
            acc[j] = __builtin_amdgcn_mfma_f32_16x16x32_bf16(af, bfj, acc[j], 0, 0, 0);
        }
    }
    #pragma unroll
    for (int r = 0; r < 4; ++r) {
        int row = bm + w * 16 + (l >> 4) * 4 + r;
        if (row < M) {
            float s = 0.f;
            #pragma unroll
            for (int j = 0; j < 8; ++j) {
                float v = acc[j][r];
                Hb[(size_t)row * OUT_DIM + j * 16 + (l & 15)] = f2bf(v);
                s += v * aw[j];
            }
            s += __shfl_xor(s, 1); s += __shfl_xor(s, 2);
            s += __shfl_xor(s, 4); s += __shfl_xor(s, 8);
            if ((l & 15) == 0) score[row] = s;
        }
    }
}

// ---------------- 2-level exclusive scan (partial offs + block offsets; no scan3)
__global__ __launch_bounds__(256) void scan1_kernel(
    const int* __restrict__ counts, int* __restrict__ offs,
    int* __restrict__ blockSums, int n) {
    __shared__ int sd[256];
    int b = blockIdx.x, tid = threadIdx.x;
    int base = b * 1024 + tid * 4;
    int v0 = base + 0 < n ? counts[base + 0] : 0;
    int v1 = base + 1 < n ? counts[base + 1] : 0;
    int v2 = base + 2 < n ? counts[base + 2] : 0;
    int v3 = base + 3 < n ? counts[base + 3] : 0;
    int p1 = v0, p2 = v0 + v1, p3 = v0 + v1 + v2;
    int tsum = p3 + v3;
    sd[tid] = tsum;
    __syncthreads();
    #pragma unroll
    for (int off = 1; off < 256; off <<= 1) {
        int t = tid >= off ? sd[tid - off] : 0;
        __syncthreads();
        sd[tid] += t;
        __syncthreads();
    }
    int ex = sd[tid] - tsum;
    if (base + 0 < n) offs[base + 0] = ex;
    if (base + 1 < n) offs[base + 1] = ex + p1;
    if (base + 2 < n) offs[base + 2] = ex + p2;
    if (base + 3 < n) offs[base + 3] = ex + p3;
    if (tid == 255) blockSums[b] = sd[255];
}

__global__ __launch_bounds__(256) void scan2_kernel(
    const int* __restrict__ blockSums, int* __restrict__ blockOffs, int nb) {
    __shared__ int sd[256];
    int tid = threadIdx.x;
    int v = tid < nb ? blockSums[tid] : 0;
    sd[tid] = v;
    __syncthreads();
    #pragma unroll
    for (int off = 1; off < 256; off <<= 1) {
        int t = tid >= off ? sd[tid - off] : 0;
        __syncthreads();
        sd[tid] += t;
        __syncthreads();
    }
    blockOffs[tid] = sd[tid] - v;
}

// ---------------- fused scatter, zero atomics; blockOffs folded in (no scan3)
__global__ __launch_bounds__(256) void scatter_fused_kernel(
    const int* __restrict__ src_id, const int* __restrict__ tgt_id,
    const float* __restrict__ score_i, const float* __restrict__ score_j,
    const int* __restrict__ offs, const int* __restrict__ blockOffs,
    const int* __restrict__ rank, uint2* __restrict__ pairs, int E) {
    int e = blockIdx.x * blockDim.x + threadIdx.x;
    if (e >= E) return;
    int s = src_id[e], t = tgt_id[e];
    float x = score_i[s] + score_j[t];
    x = x > 0.f ? x : LEAKY * x;
    x = fminf(30.f, fmaxf(-30.f, x));
    float ex = expf(x);
    int p = offs[s] + blockOffs[s >> 10] + rank[e];
    pairs[p] = make_uint2((unsigned int)t, __float_as_uint(ex));
}

// ---------------- aggregate (round-8 proven 4-edge): wave per node, inline denom, fused ELU
__global__ __launch_bounds__(256) void agg_kernel(
    const uint2* __restrict__ pairs, const int* __restrict__ offs,
    const int* __restrict__ blockOffs, const unsigned short* __restrict__ hjb,
    float* __restrict__ out, int N, int E) {
    int node = (int)((blockIdx.x * (long long)blockDim.x + threadIdx.x) >> 6);
    if (node >= N) return;
    int lane = threadIdx.x & 63;
    int q  = lane >> 4;   // quarter-group: edges e ≡ q (mod 4)
    int cl = lane & 15;   // column lane: owns cols cl*8 .. cl*8+7
    int beg = offs[node] + blockOffs[node >> 10];
    int end = (node + 1 < N) ? offs[node + 1] + blockOffs[(node + 1) >> 10] : E;
    int deg = end - beg;
    float den = 0.f;
    float acc[8];
    #pragma unroll
    for (int i = 0; i < 8; ++i) acc[i] = 0.f;

    int iters = (deg + 3) >> 2;               // uniform across the wave
    for (int it = 0; it < iters; ++it) {
        int e = q + 4 * it;
        bool valid = e < deg;
        int idx = beg + (valid ? e : 0);
        uint2 tw = pairs[idx];                // same addr in 16-lane group -> broadcast
        int t = (int)tw.x;
        float wgt = valid ? __uint_as_float(tw.y) : 0.f;
        den += wgt;
        uint4 u = *(const uint4*)(hjb + (size_t)t * OUT_DIM + cl * 8);
        acc[0] += bf2f(u.x & 0xffffu) * wgt;
        acc[1] += bf2f(u.x >> 16) * wgt;
        acc[2] += bf2f(u.y & 0xffffu) * wgt;
        acc[3] += bf2f(u.y >> 16) * wgt;
        acc[4] += bf2f(u.z & 0xffffu) * wgt;
        acc[5] += bf2f(u.z >> 16) * wgt;
        acc[6] += bf2f(u.w & 0xffffu) * wgt;
        acc[7] += bf2f(u.w >> 16) * wgt;
    }
    den += __shfl_xor(den, 16);
    den += __shfl_xor(den, 32);
    float inv = 1.f / (den + 1e-8f);
    #pragma unroll
    for (int i = 0; i < 8; ++i) {
        acc[i] += __shfl_xor(acc[i], 16);
        acc[i] += __shfl_xor(acc[i], 32);
        acc[i] *= inv;
        acc[i] = acc[i] > 0.f ? acc[i] : expm1f(acc[i]);
    }
    if (lane < 16) {
        float4 v0 = make_float4(acc[0], acc[1], acc[2], acc[3]);
        float4 v1 = make_float4(acc[4], acc[5], acc[6], acc[7]);
        *(float4*)(out + (size_t)node * OUT_DIM + cl * 8) = v0;
        *(float4*)(out + (size_t)node * OUT_DIM + cl * 8 + 4) = v1;
    }
}

// ---------------- fallback path (atomic scatter) if ws too small
__global__ __launch_bounds__(256) void edge_pass1_kernel(
    const int* __restrict__ src_id, const int* __restrict__ tgt_id,
    const float* __restrict__ score_i, const float* __restrict__ score_j,
    float* __restrict__ exp_e, float* __restrict__ denom, int E) {
    int e = blockIdx.x * blockDim.x + threadIdx.x;
    if (e >= E) return;
    int s = src_id[e], t = tgt_id[e];
    float x = score_i[s] + score_j[t];
    x = x > 0.f ? x : LEAKY * x;
    x = fminf(30.f, fmaxf(-30.f, x));
    float ex = expf(x);
    exp_e[e] = ex;
    atomicAdd(&denom[s], ex);
}

__global__ __launch_bounds__(256) void edge_pass2_kernel(
    const int* __restrict__ src_id, const int* __restrict__ tgt_id,
    const unsigned short* __restrict__ hjb, const float* __restrict__ exp_e,
    const float* __restrict__ denom, float* __restrict__ out, int E) {
    int idx = blockIdx.x * blockDim.x + threadIdx.x;
    int e = idx >> 6;
    if (e >= E) return;
    int lane = idx & 63;
    int s = src_id[e], t = tgt_id[e];
    float alpha = exp_e[e] / (denom[s] + 1e-8f);
    unsigned int u = *(const unsigned int*)(hjb + (size_t)t * OUT_DIM + lane * 2);
    atomicAdd(out + (size_t)s * OUT_DIM + lane * 2 + 0, bf2f(u & 0xffffu) * alpha);
    atomicAdd(out + (size_t)s * OUT_DIM + lane * 2 + 1, bf2f(u >> 16) * alpha);
}

__global__ __launch_bounds__(256) void elu_kernel(float* __restrict__ out, int n4) {
    int i = blockIdx.x * blockDim.x + threadIdx.x;
    if (i >= n4) return;
    float4 v = ((float4*)out)[i];
    v.x = v.x > 0.f ? v.x : expm1f(v.x);
    v.y = v.y > 0.f ? v.y : expm1f(v.y);
    v.z = v.z > 0.f ? v.z : expm1f(v.z);
    v.w = v.w > 0.f ? v.w : expm1f(v.w);
    ((float4*)out)[i] = v;
}

extern "C" void kernel_launch(void* const* d_in, const int* in_sizes, int n_in,
                              void* d_out, int out_size, void* d_ws, size_t ws_size,
                              hipStream_t stream) {
    const float* src   = (const float*)d_in[0];
    const float* tgt   = (const float*)d_in[1];
    const float* W_src = (const float*)d_in[2];
    const float* W_tgt = (const float*)d_in[3];
    const float* a     = (const float*)d_in[4];
    const int*   edge  = (const int*)d_in[5];

    int N_src = in_sizes[0] / IN_DIM;
    int N_tgt = in_sizes[1] / IN_DIM;
    int E     = in_sizes[5] / 2;
    const int* src_id = edge;
    const int* tgt_id = edge + E;

    float* out = (float*)d_out;

    char* ws = (char*)d_ws;
    size_t off = 0;
    auto alloc = [&](size_t bytes) {
        void* p = ws + off;
        off += (bytes + 255) & ~(size_t)255;
        return p;
    };

    unsigned short* hjb  = (unsigned short*)alloc((size_t)N_tgt * OUT_DIM * 2);
    float* score_i = (float*)alloc((size_t)N_src * 4);
    float* score_j = (float*)alloc((size_t)N_tgt * 4);
    float* wcomb   = (float*)alloc(256 * 4);
    unsigned short* Wswz = (unsigned short*)alloc(4096 * 8 * 2);
    int*   counts    = (int*)alloc((size_t)N_src * 4);
    int*   offs      = (int*)alloc((size_t)(N_src + 1) * 4);
    int*   blockSums = (int*)alloc(256 * 4);
    int*   blockOffs = (int*)alloc(256 * 4);
    float* denom     = (float*)alloc((size_t)N_src * 4);   // fallback only
    float* exp_e     = (float*)alloc((size_t)E * 4);       // fallback only
    size_t fb_need = off;
    int*   rank      = (int*)alloc((size_t)E * 4);
    uint2* pairs     = (uint2*)alloc((size_t)E * 8);
    size_t csr_need = off;
    (void)fb_need;

    bool use_csr = (ws_size >= csr_need);

    prep_kernel<<<17, 256, 0, stream>>>(W_src, W_tgt, a, wcomb, Wswz);

    if (use_csr) {
        hipMemsetAsync(counts, 0, (size_t)N_src * sizeof(int), stream);
        int gemvBlocks = (N_src + 3) / 4;
        int histBlocks = (E + 255) / 256;
        int g7 = (gemvBlocks + 6) / 7;
        int T = 8 * (histBlocks > g7 ? histBlocks : g7);
        gemv_hist_kernel<<<T, 256, 0, stream>>>(
            src, wcomb, score_i, N_src, src_id, counts, rank, E);
        gemm_mfma_kernel<<<(N_tgt + 63) / 64, 256, 0, stream>>>(
            tgt, Wswz, a + OUT_DIM, hjb, score_j, N_tgt);
        int nb = (N_src + 1023) / 1024;
        scan1_kernel<<<nb, 256, 0, stream>>>(counts, offs, blockSums, N_src);
        scan2_kernel<<<1, 256, 0, stream>>>(blockSums, blockOffs, nb);
        scatter_fused_kernel<<<(E + 255) / 256, 256, 0, stream>>>(
            src_id, tgt_id, score_i, score_j, offs, blockOffs, rank, pairs, E);
        agg_kernel<<<(N_src + 3) / 4, 256, 0, stream>>>(
            pairs, offs, blockOffs, hjb, out, N_src, E);
    } else {
        int gemvBlocks = (N_src + 3) / 4;
        gemv_hist_kernel<<<8 * ((gemvBlocks + 6) / 7), 256, 0, stream>>>(
            src, wcomb, score_i, N_src, src_id, counts, rank, 0);
        gemm_mfma_kernel<<<(N_tgt + 63) / 64, 256, 0, stream>>>(
            tgt, Wswz, a + OUT_DIM, hjb, score_j, N_tgt);
        hipMemsetAsync(out, 0, (size_t)N_src * OUT_DIM * sizeof(float), stream);
        hipMemsetAsync(denom, 0, (size_t)N_src * sizeof(float), stream);
        edge_pass1_kernel<<<(E + 255) / 256, 256, 0, stream>>>(
            src_id, tgt_id, score_i, score_j, exp_e, denom, E);
        edge_pass2_kernel<<<(int)(((long long)E * 64 + 255) / 256), 256, 0, stream>>>(
            src_id, tgt_id, hjb, exp_e, denom, out, E);
        elu_kernel<<<(N_src * OUT_DIM / 4 + 255) / 256, 256, 0, stream>>>(
            out, N_src * OUT_DIM / 4);
    }
}

// Round 11
// 152.287 us; speedup vs baseline: 1.2707x; 1.1319x over previous
//
#include <hip/hip_runtime.h>
#include <hip/hip_bf16.h>
#include <math.h>

#define IN_DIM 256
#define OUT_DIM 128
#define LEAKY 0.2f

typedef __attribute__((ext_vector_type(8))) short bf16x8;
typedef __attribute__((ext_vector_type(4))) float f32x4;

__device__ __forceinline__ unsigned short f2bf(float f) {
    union { float f; unsigned int u; } v; v.f = f;
    unsigned int r = v.u + 0x7FFFu + ((v.u >> 16) & 1u);
    return (unsigned short)(r >> 16);
}
__device__ __forceinline__ float bf2f(unsigned int hi16) {
    union { unsigned int u; float f; } v; v.u = hi16 << 16;
    return v.f;
}

// ---------------- prep: blocks 0..15 = wswz (W_tgt -> bf16 fragment-major),
//                  block 16 = wcomb = W_src @ a[0:128], blocks 17.. zero counts
__global__ __launch_bounds__(256) void prep_kernel(
    const float* __restrict__ W_src, const float* __restrict__ W_tgt,
    const float* __restrict__ a, float* __restrict__ wcomb,
    unsigned short* __restrict__ Wswz, int4* __restrict__ counts4, int n4) {
    if (blockIdx.x >= 17) {
        int i = (blockIdx.x - 17) * 256 + threadIdx.x;
        if (i < n4) counts4[i] = make_int4(0, 0, 0, 0);
        return;
    }
    if (blockIdx.x == 16) {
        int i = threadIdx.x;
        float s = 0.f;
        #pragma unroll 4
        for (int k = 0; k < OUT_DIM; ++k) s += W_src[i * OUT_DIM + k] * a[k];
        wcomb[i] = s;
        return;
    }
    int idx = blockIdx.x * 256 + threadIdx.x;   // 0..4095
    int l  = idx & 63;
    int fj = (idx >> 6) & 7;
    int kc = idx >> 9;
    int col = fj * 16 + (l & 15);
    int kb  = kc * 32 + (l >> 4) * 8;
    unsigned int u[4];
    #pragma unroll
    for (int p = 0; p < 4; ++p) {
        unsigned short e0 = f2bf(W_tgt[(size_t)(kb + 2 * p + 0) * OUT_DIM + col]);
        unsigned short e1 = f2bf(W_tgt[(size_t)(kb + 2 * p + 1) * OUT_DIM + col]);
        u[p] = (unsigned int)e0 | ((unsigned int)e1 << 16);
    }
    *(uint4*)(Wswz + (size_t)idx * 8) = make_uint4(u[0], u[1], u[2], u[3]);
}

// ---------------- FUSED (1:1): score_i GEMV (even blocks) + hist/rank (odd blocks)
// GEMV: 8 lanes per row, 8 x float4 per lane (ILP 8), 32 rows per block.
__global__ __launch_bounds__(256) void gemv_hist_kernel(
    const float* __restrict__ X, const float* __restrict__ w,
    float* __restrict__ score, int M,
    const int* __restrict__ src_id, int* __restrict__ counts,
    int* __restrict__ rank, int E) {
    int bid = blockIdx.x;
    if (bid & 1) {
        int e = (bid >> 1) * 256 + threadIdx.x;
        if (e < E) rank[e] = atomicAdd(&counts[src_id[e]], 1);
        return;
    }
    int row = (bid >> 1) * 32 + (threadIdx.x >> 3);
    if (row >= M) return;
    int k = threadIdx.x & 7;
    const float4* R = (const float4*)(X + (size_t)row * IN_DIM);
    const float4* W4 = (const float4*)w;
    float s = 0.f;
    #pragma unroll
    for (int c = 0; c < 8; ++c) {
        float4 x = R[k + 8 * c];
        float4 wv = W4[k + 8 * c];
        s += x.x * wv.x + x.y * wv.y + x.z * wv.z + x.w * wv.w;
    }
    s += __shfl_xor(s, 1);
    s += __shfl_xor(s, 2);
    s += __shfl_xor(s, 4);
    if (k == 0) score[row] = s;
}

// ---------------- MFMA GEMM: single-phase full-K staging (32 KB LDS, 1 barrier)
__global__ __launch_bounds__(256) void gemm_mfma_kernel(
    const float* __restrict__ A,            // [M,256] f32
    const unsigned short* __restrict__ Wswz,// fragment-major bf16
    const float* __restrict__ a_hi,         // [128]
    unsigned short* __restrict__ Hb,        // [M,128] bf16
    float* __restrict__ score, int M) {
    __shared__ unsigned short As[64 * 256];  // 32 KB, XOR-swizzled
    int tid = threadIdx.x;
    int w = tid >> 6;
    int l = tid & 63;
    int bm = blockIdx.x * 64;

    int srow = tid >> 4;
    int kcol = (tid & 15) * 4;

    float aw[8];
    #pragma unroll
    for (int j = 0; j < 8; ++j) aw[j] = a_hi[j * 16 + (l & 15)];

    f32x4 acc[8];
    f32x4 zero = {0.f, 0.f, 0.f, 0.f};
    #pragma unroll
    for (int j = 0; j < 8; ++j) acc[j] = zero;

    float4 pre[16];
    #pragma unroll
    for (int p = 0; p < 4; ++p) {
        int grow = bm + srow + p * 16;
        const float* rp = A + (size_t)(grow < M ? grow : M - 1) * IN_DIM;
        bool ok = grow < M;
        #pragma unroll
        for (int c = 0; c < 4; ++c) {
            float4 v = *(const float4*)(rp + c * 64 + kcol);
            pre[p * 4 + c] = ok ? v : make_float4(0.f, 0.f, 0.f, 0.f);
        }
    }
    #pragma unroll
    for (int p = 0; p < 4; ++p) {
        int row = srow + p * 16;
        #pragma unroll
        for (int c = 0; c < 4; ++c) {
            float4 v = pre[p * 4 + c];
            unsigned int b0 = (unsigned int)f2bf(v.x) | ((unsigned int)f2bf(v.y) << 16);
            unsigned int b1 = (unsigned int)f2bf(v.z) | ((unsigned int)f2bf(v.w) << 16);
            unsigned int byteoff =
                (unsigned int)(row * 512 + (c * 64 + kcol) * 2) ^ ((row & 7) << 4);
            *(uint2*)((char*)As + byteoff) = make_uint2(b0, b1);
        }
    }
    __syncthreads();

    #pragma unroll
    for (int kc = 0; kc < 8; ++kc) {
        int row = w * 16 + (l & 15);
        unsigned int byteoff =
            (unsigned int)(row * 512 + kc * 64 + (l >> 4) * 16) ^ ((row & 7) << 4);
        bf16x8 af = *(const bf16x8*)((const char*)As + byteoff);
        #pragma unroll
        for (int j = 0; j < 8; ++j) {
            bf16x8 bfj = *(const bf16x8*)(Wswz + ((size_t)(kc * 8 + j) * 64 + l) * 8);
            acc[j] = __builtin_amdgcn_mfma_f32_16x16x32_bf16(af, bfj, acc[j], 0, 0, 0);
        }
    }
    #pragma unroll
    for (int r = 0; r < 4; ++r) {
        int row = bm + w * 16 + (l >> 4) * 4 + r;
        if (row < M) {
            float s = 0.f;
            #pragma unroll
            for (int j = 0; j < 8; ++j) {
                float v = acc[j][r];
                Hb[(size_t)row * OUT_DIM + j * 16 + (l & 15)] = f2bf(v);
                s += v * aw[j];
            }
            s += __shfl_xor(s, 1); s += __shfl_xor(s, 2);
            s += __shfl_xor(s, 4); s += __shfl_xor(s, 8);
            if ((l & 15) == 0) score[row] = s;
        }
    }
}

// ---------------- 2-level exclusive scan (partial offs + block offsets)
__global__ __launch_bounds__(256) void scan1_kernel(
    const int* __restrict__ counts, int* __restrict__ offs,
    int* __restrict__ blockSums, int n) {
    __shared__ int sd[256];
    int b = blockIdx.x, tid = threadIdx.x;
    int base = b * 1024 + tid * 4;
    int v0 = base + 0 < n ? counts[base + 0] : 0;
    int v1 = base + 1 < n ? counts[base + 1] : 0;
    int v2 = base + 2 < n ? counts[base + 2] : 0;
    int v3 = base + 3 < n ? counts[base + 3] : 0;
    int p1 = v0, p2 = v0 + v1, p3 = v0 + v1 + v2;
    int tsum = p3 + v3;
    sd[tid] = tsum;
    __syncthreads();
    #pragma unroll
    for (int off = 1; off < 256; off <<= 1) {
        int t = tid >= off ? sd[tid - off] : 0;
        __syncthreads();
        sd[tid] += t;
        __syncthreads();
    }
    int ex = sd[tid] - tsum;
    if (base + 0 < n) offs[base + 0] = ex;
    if (base + 1 < n) offs[base + 1] = ex + p1;
    if (base + 2 < n) offs[base + 2] = ex + p2;
    if (base + 3 < n) offs[base + 3] = ex + p3;
    if (tid == 255) blockSums[b] = sd[255];
}

__global__ __launch_bounds__(256) void scan2_kernel(
    const int* __restrict__ blockSums, int* __restrict__ blockOffs, int nb) {
    __shared__ int sd[256];
    int tid = threadIdx.x;
    int v = tid < nb ? blockSums[tid] : 0;
    sd[tid] = v;
    __syncthreads();
    #pragma unroll
    for (int off = 1; off < 256; off <<= 1) {
        int t = tid >= off ? sd[tid - off] : 0;
        __syncthreads();
        sd[tid] += t;
        __syncthreads();
    }
    blockOffs[tid] = sd[tid] - v;
}

// ---------------- fused scatter, zero atomics; blockOffs folded in
__global__ __launch_bounds__(256) void scatter_fused_kernel(
    const int* __restrict__ src_id, const int* __restrict__ tgt_id,
    const float* __restrict__ score_i, const float* __restrict__ score_j,
    const int* __restrict__ offs, const int* __restrict__ blockOffs,
    const int* __restrict__ rank, uint2* __restrict__ pairs, int E) {
    int e = blockIdx.x * blockDim.x + threadIdx.x;
    if (e >= E) return;
    int s = src_id[e], t = tgt_id[e];
    float x = score_i[s] + score_j[t];
    x = x > 0.f ? x : LEAKY * x;
    x = fminf(30.f, fmaxf(-30.f, x));
    float ex = expf(x);
    int p = offs[s] + blockOffs[s >> 10] + rank[e];
    pairs[p] = make_uint2((unsigned int)t, __float_as_uint(ex));
}

// ---------------- aggregate: wave per node, 4 edges in flight, inline denom, fused ELU
__global__ __launch_bounds__(256) void agg_kernel(
    const uint2* __restrict__ pairs, const int* __restrict__ offs,
    const int* __restrict__ blockOffs, const unsigned short* __restrict__ hjb,
    float* __restrict__ out, int N, int E) {
    int node = (int)((blockIdx.x * (long long)blockDim.x + threadIdx.x) >> 6);
    if (node >= N) return;
    int lane = threadIdx.x & 63;
    int q  = lane >> 4;
    int cl = lane & 15;
    int beg = offs[node] + blockOffs[node >> 10];
    int end = (node + 1 < N) ? offs[node + 1] + blockOffs[(node + 1) >> 10] : E;
    int deg = end - beg;
    float den = 0.f;
    float acc[8];
    #pragma unroll
    for (int i = 0; i < 8; ++i) acc[i] = 0.f;

    int iters = (deg + 3) >> 2;
    for (int it = 0; it < iters; ++it) {
        int e = q + 4 * it;
        bool valid = e < deg;
        int idx = beg + (valid ? e : 0);
        uint2 tw = pairs[idx];
        int t = (int)tw.x;
        float wgt = valid ? __uint_as_float(tw.y) : 0.f;
        den += wgt;
        uint4 u = *(const uint4*)(hjb + (size_t)t * OUT_DIM + cl * 8);
        acc[0] += bf2f(u.x & 0xffffu) * wgt;
        acc[1] += bf2f(u.x >> 16) * wgt;
        acc[2] += bf2f(u.y & 0xffffu) * wgt;
        acc[3] += bf2f(u.y >> 16) * wgt;
        acc[4] += bf2f(u.z & 0xffffu) * wgt;
        acc[5] += bf2f(u.z >> 16) * wgt;
        acc[6] += bf2f(u.w & 0xffffu) * wgt;
        acc[7] += bf2f(u.w >> 16) * wgt;
    }
    den += __shfl_xor(den, 16);
    den += __shfl_xor(den, 32);
    float inv = 1.f / (den + 1e-8f);
    #pragma unroll
    for (int i = 0; i < 8; ++i) {
        acc[i] += __shfl_xor(acc[i], 16);
        acc[i] += __shfl_xor(acc[i], 32);
        acc[i] *= inv;
        acc[i] = acc[i] > 0.f ? acc[i] : expm1f(acc[i]);
    }
    if (lane < 16) {
        float4 v0 = make_float4(acc[0], acc[1], acc[2], acc[3]);
        float4 v1 = make_float4(acc[4], acc[5], acc[6], acc[7]);
        *(float4*)(out + (size_t)node * OUT_DIM + cl * 8) = v0;
        *(float4*)(out + (size_t)node * OUT_DIM + cl * 8 + 4) = v1;
    }
}

// ---------------- fallback path (atomic scatter) if ws too small
__global__ __launch_bounds__(256) void edge_pass1_kernel(
    const int* __restrict__ src_id, const int* __restrict__ tgt_id,
    const float* __restrict__ score_i, const float* __restrict__ score_j,
    float* __restrict__ exp_e, float* __restrict__ denom, int E) {
    int e = blockIdx.x * blockDim.x + threadIdx.x;
    if (e >= E) return;
    int s = src_id[e], t = tgt_id[e];
    float x = score_i[s] + score_j[t];
    x = x > 0.f ? x : LEAKY * x;
    x = fminf(30.f, fmaxf(-30.f, x));
    float ex = expf(x);
    exp_e[e] = ex;
    atomicAdd(&denom[s], ex);
}

__global__ __launch_bounds__(256) void edge_pass2_kernel(
    const int* __restrict__ src_id, const int* __restrict__ tgt_id,
    const unsigned short* __restrict__ hjb, const float* __restrict__ exp_e,
    const float* __restrict__ denom, float* __restrict__ out, int E) {
    int idx = blockIdx.x * blockDim.x + threadIdx.x;
    int e = idx >> 6;
    if (e >= E) return;
    int lane = idx & 63;
    int s = src_id[e], t = tgt_id[e];
    float alpha = exp_e[e] / (denom[s] + 1e-8f);
    unsigned int u = *(const unsigned int*)(hjb + (size_t)t * OUT_DIM + lane * 2);
    atomicAdd(out + (size_t)s * OUT_DIM + lane * 2 + 0, bf2f(u & 0xffffu) * alpha);
    atomicAdd(out + (size_t)s * OUT_DIM + lane * 2 + 1, bf2f(u >> 16) * alpha);
}

__global__ __launch_bounds__(256) void elu_kernel(float* __restrict__ out, int n4) {
    int i = blockIdx.x * blockDim.x + threadIdx.x;
    if (i >= n4) return;
    float4 v = ((float4*)out)[i];
    v.x = v.x > 0.f ? v.x : expm1f(v.x);
    v.y = v.y > 0.f ? v.y : expm1f(v.y);
    v.z = v.z > 0.f ? v.z : expm1f(v.z);
    v.w = v.w > 0.f ? v.w : expm1f(v.w);
    ((float4*)out)[i] = v;
}

extern "C" void kernel_launch(void* const* d_in, const int* in_sizes, int n_in,
                              void* d_out, int out_size, void* d_ws, size_t ws_size,
                              hipStream_t stream) {
    const float* src   = (const float*)d_in[0];
    const float* tgt   = (const float*)d_in[1];
    const float* W_src = (const float*)d_in[2];
    const float* W_tgt = (const float*)d_in[3];
    const float* a     = (const float*)d_in[4];
    const int*   edge  = (const int*)d_in[5];

    int N_src = in_sizes[0] / IN_DIM;
    int N_tgt = in_sizes[1] / IN_DIM;
    int E     = in_sizes[5] / 2;
    const int* src_id = edge;
    const int* tgt_id = edge + E;

    float* out = (float*)d_out;

    char* ws = (char*)d_ws;
    size_t off = 0;
    auto alloc = [&](size_t bytes) {
        void* p = ws + off;
        off += (bytes + 255) & ~(size_t)255;
        return p;
    };

    unsigned short* hjb  = (unsigned short*)alloc((size_t)N_tgt * OUT_DIM * 2);
    float* score_i = (float*)alloc((size_t)N_src * 4);
    float* score_j = (float*)alloc((size_t)N_tgt * 4);
    float* wcomb   = (float*)alloc(256 * 4);
    unsigned short* Wswz = (unsigned short*)alloc(4096 * 8 * 2);
    int*   counts    = (int*)alloc(((size_t)N_src + 3) / 4 * 16);  // int4-aligned
    int*   offs      = (int*)alloc((size_t)(N_src + 1) * 4);
    int*   blockSums = (int*)alloc(256 * 4);
    int*   blockOffs = (int*)alloc(256 * 4);
    float* denom     = (float*)alloc((size_t)N_src * 4);   // fallback only
    float* exp_e     = (float*)alloc((size_t)E * 4);       // fallback only
    size_t fb_need = off;
    int*   rank      = (int*)alloc((size_t)E * 4);
    uint2* pairs     = (uint2*)alloc((size_t)E * 8);
    size_t csr_need = off;
    (void)fb_need;

    bool use_csr = (ws_size >= csr_need);

    int n4 = (N_src + 3) / 4;                 // count of int4s to zero
    int zblocks = (n4 + 255) / 256;
    prep_kernel<<<17 + zblocks, 256, 0, stream>>>(
        W_src, W_tgt, a, wcomb, Wswz, (int4*)counts, n4);

    if (use_csr) {
        int gemvBlocks = (N_src + 31) / 32;
        int histBlocks = (E + 255) / 256;
        int half = gemvBlocks > histBlocks ? gemvBlocks : histBlocks;
        gemv_hist_kernel<<<2 * half, 256, 0, stream>>>(
            src, wcomb, score_i, N_src, src_id, counts, rank, E);
        gemm_mfma_kernel<<<(N_tgt + 63) / 64, 256, 0, stream>>>(
            tgt, Wswz, a + OUT_DIM, hjb, score_j, N_tgt);
        int nb = (N_src + 1023) / 1024;
        scan1_kernel<<<nb, 256, 0, stream>>>(counts, offs, blockSums, N_src);
        scan2_kernel<<<1, 256, 0, stream>>>(blockSums, blockOffs, nb);
        scatter_fused_kernel<<<(E + 255) / 256, 256, 0, stream>>>(
            src_id, tgt_id, score_i, score_j, offs, blockOffs, rank, pairs, E);
        agg_kernel<<<(N_src + 3) / 4, 256, 0, stream>>>(
            pairs, offs, blockOffs, hjb, out, N_src, E);
    } else {
        int gemvBlocks = (N_src + 31) / 32;
        gemv_hist_kernel<<<2 * gemvBlocks, 256, 0, stream>>>(
            src, wcomb, score_i, N_src, src_id, counts, rank, 0);
        gemm_mfma_kernel<<<(N_tgt + 63) / 64, 256, 0, stream>>>(
            tgt, Wswz, a + OUT_DIM, hjb, score_j, N_tgt);
        hipMemsetAsync(out, 0, (size_t)N_src * OUT_DIM * sizeof(float), stream);
        hipMemsetAsync(denom, 0, (size_t)N_src * sizeof(float), stream);
        edge_pass1_kernel<<<(E + 255) / 256, 256, 0, stream>>>(
            src_id, tgt_id, score_i, score_j, exp_e, denom, E);
        edge_pass2_kernel<<<(int)(((long long)E * 64 + 255) / 256), 256, 0, stream>>>(
            src_id, tgt_id, hjb, exp_e, denom, out, E);
        elu_kernel<<<(N_src * OUT_DIM / 4 + 255) / 256, 256, 0, stream>>>(
            out, N_src * OUT_DIM / 4);
    }
}

// Round 12
// 151.036 us; speedup vs baseline: 1.2812x; 1.0083x over previous
//
#include <hip/hip_runtime.h>
#include <hip/hip_bf16.h>
#include <math.h>

#define IN_DIM 256
#define OUT_DIM 128
#define LEAKY 0.2f

typedef __attribute__((ext_vector_type(8))) short bf16x8;
typedef __attribute__((ext_vector_type(4))) float f32x4;

__device__ __forceinline__ unsigned short f2bf(float f) {
    union { float f; unsigned int u; } v; v.f = f;
    unsigned int r = v.u + 0x7FFFu + ((v.u >> 16) & 1u);
    return (unsigned short)(r >> 16);
}
__device__ __forceinline__ float bf2f(unsigned int hi16) {
    union { unsigned int u; float f; } v; v.u = hi16 << 16;
    return v.f;
}

// ---------------- prep: blocks 0..15 = wswz (W_tgt -> bf16 fragment-major),
//                  block 16 = wcomb = W_src @ a[0:128], blocks 17.. zero counts
__global__ __launch_bounds__(256) void prep_kernel(
    const float* __restrict__ W_src, const float* __restrict__ W_tgt,
    const float* __restrict__ a, float* __restrict__ wcomb,
    unsigned short* __restrict__ Wswz, int4* __restrict__ counts4, int n4) {
    if (blockIdx.x >= 17) {
        int i = (blockIdx.x - 17) * 256 + threadIdx.x;
        if (i < n4) counts4[i] = make_int4(0, 0, 0, 0);
        return;
    }
    if (blockIdx.x == 16) {
        int i = threadIdx.x;
        float s = 0.f;
        #pragma unroll 4
        for (int k = 0; k < OUT_DIM; ++k) s += W_src[i * OUT_DIM + k] * a[k];
        wcomb[i] = s;
        return;
    }
    int idx = blockIdx.x * 256 + threadIdx.x;   // 0..4095
    int l  = idx & 63;
    int fj = (idx >> 6) & 7;
    int kc = idx >> 9;
    int col = fj * 16 + (l & 15);
    int kb  = kc * 32 + (l >> 4) * 8;
    unsigned int u[4];
    #pragma unroll
    for (int p = 0; p < 4; ++p) {
        unsigned short e0 = f2bf(W_tgt[(size_t)(kb + 2 * p + 0) * OUT_DIM + col]);
        unsigned short e1 = f2bf(W_tgt[(size_t)(kb + 2 * p + 1) * OUT_DIM + col]);
        u[p] = (unsigned int)e0 | ((unsigned int)e1 << 16);
    }
    *(uint4*)(Wswz + (size_t)idx * 8) = make_uint4(u[0], u[1], u[2], u[3]);
}

// ---------------- FUSED (1:1): score_i GEMV (even blocks) + hist/rank (odd blocks)
// GEMV: 8 lanes per row, 8 x float4 per lane (ILP 8), 32 rows per block.
__global__ __launch_bounds__(256) void gemv_hist_kernel(
    const float* __restrict__ X, const float* __restrict__ w,
    float* __restrict__ score, int M,
    const int* __restrict__ src_id, int* __restrict__ counts,
    int* __restrict__ rank, int E) {
    int bid = blockIdx.x;
    if (bid & 1) {
        int e = (bid >> 1) * 256 + threadIdx.x;
        if (e < E) rank[e] = atomicAdd(&counts[src_id[e]], 1);
        return;
    }
    int row = (bid >> 1) * 32 + (threadIdx.x >> 3);
    if (row >= M) return;
    int k = threadIdx.x & 7;
    const float4* R = (const float4*)(X + (size_t)row * IN_DIM);
    const float4* W4 = (const float4*)w;
    float s = 0.f;
    #pragma unroll
    for (int c = 0; c < 8; ++c) {
        float4 x = R[k + 8 * c];
        float4 wv = W4[k + 8 * c];
        s += x.x * wv.x + x.y * wv.y + x.z * wv.z + x.w * wv.w;
    }
    s += __shfl_xor(s, 1);
    s += __shfl_xor(s, 2);
    s += __shfl_xor(s, 4);
    if (k == 0) score[row] = s;
}

// ---------------- MFMA GEMM: 32-row tile, 128 threads, 16 KB LDS (occupancy 10 blk/CU)
// Addressing formulas identical to the proven 64-row version; bm = blockIdx.x*32.
__global__ __launch_bounds__(128) void gemm_mfma_kernel(
    const float* __restrict__ A,            // [M,256] f32
    const unsigned short* __restrict__ Wswz,// fragment-major bf16
    const float* __restrict__ a_hi,         // [128]
    unsigned short* __restrict__ Hb,        // [M,128] bf16
    float* __restrict__ score, int M) {
    __shared__ unsigned short As[32 * 256];  // 16 KB, XOR-swizzled
    int tid = threadIdx.x;
    int w = tid >> 6;                        // 0..1
    int l = tid & 63;
    int bm = blockIdx.x * 32;

    int srow = tid >> 4;                     // 0..7 (staging row base)
    int kcol = (tid & 15) * 4;               // 0..60

    float aw[8];
    #pragma unroll
    for (int j = 0; j < 8; ++j) aw[j] = a_hi[j * 16 + (l & 15)];

    f32x4 acc[8];
    f32x4 zero = {0.f, 0.f, 0.f, 0.f};
    #pragma unroll
    for (int j = 0; j < 8; ++j) acc[j] = zero;

    // issue ALL staging loads (ILP 16), then convert+write, one barrier
    float4 pre[16];
    #pragma unroll
    for (int p = 0; p < 4; ++p) {
        int grow = bm + srow + p * 8;
        const float* rp = A + (size_t)(grow < M ? grow : M - 1) * IN_DIM;
        bool ok = grow < M;
        #pragma unroll
        for (int c = 0; c < 4; ++c) {
            float4 v = *(const float4*)(rp + c * 64 + kcol);
            pre[p * 4 + c] = ok ? v : make_float4(0.f, 0.f, 0.f, 0.f);
        }
    }
    #pragma unroll
    for (int p = 0; p < 4; ++p) {
        int row = srow + p * 8;
        #pragma unroll
        for (int c = 0; c < 4; ++c) {
            float4 v = pre[p * 4 + c];
            unsigned int b0 = (unsigned int)f2bf(v.x) | ((unsigned int)f2bf(v.y) << 16);
            unsigned int b1 = (unsigned int)f2bf(v.z) | ((unsigned int)f2bf(v.w) << 16);
            unsigned int byteoff =
                (unsigned int)(row * 512 + (c * 64 + kcol) * 2) ^ ((row & 7) << 4);
            *(uint2*)((char*)As + byteoff) = make_uint2(b0, b1);
        }
    }
    __syncthreads();

    #pragma unroll
    for (int kc = 0; kc < 8; ++kc) {
        int row = w * 16 + (l & 15);
        unsigned int byteoff =
            (unsigned int)(row * 512 + kc * 64 + (l >> 4) * 16) ^ ((row & 7) << 4);
        bf16x8 af = *(const bf16x8*)((const char*)As + byteoff);
        #pragma unroll
        for (int j = 0; j < 8; ++j) {
            bf16x8 bfj = *(const bf16x8*)(Wswz + ((size_t)(kc * 8 + j) * 64 + l) * 8);
            acc[j] = __builtin_amdgcn_mfma_f32_16x16x32_bf16(af, bfj, acc[j], 0, 0, 0);
        }
    }
    #pragma unroll
    for (int r = 0; r < 4; ++r) {
        int row = bm + w * 16 + (l >> 4) * 4 + r;
        if (row < M) {
            float s = 0.f;
            #pragma unroll
            for (int j = 0; j < 8; ++j) {
                float v = acc[j][r];
                Hb[(size_t)row * OUT_DIM + j * 16 + (l & 15)] = f2bf(v);
                s += v * aw[j];
            }
            s += __shfl_xor(s, 1); s += __shfl_xor(s, 2);
            s += __shfl_xor(s, 4); s += __shfl_xor(s, 8);
            if ((l & 15) == 0) score[row] = s;
        }
    }
}

// ---------------- 2-level exclusive scan (partial offs + block offsets)
__global__ __launch_bounds__(256) void scan1_kernel(
    const int* __restrict__ counts, int* __restrict__ offs,
    int* __restrict__ blockSums, int n) {
    __shared__ int sd[256];
    int b = blockIdx.x, tid = threadIdx.x;
    int base = b * 1024 + tid * 4;
    int v0 = base + 0 < n ? counts[base + 0] : 0;
    int v1 = base + 1 < n ? counts[base + 1] : 0;
    int v2 = base + 2 < n ? counts[base + 2] : 0;
    int v3 = base + 3 < n ? counts[base + 3] : 0;
    int p1 = v0, p2 = v0 + v1, p3 = v0 + v1 + v2;
    int tsum = p3 + v3;
    sd[tid] = tsum;
    __syncthreads();
    #pragma unroll
    for (int off = 1; off < 256; off <<= 1) {
        int t = tid >= off ? sd[tid - off] : 0;
        __syncthreads();
        sd[tid] += t;
        __syncthreads();
    }
    int ex = sd[tid] - tsum;
    if (base + 0 < n) offs[base + 0] = ex;
    if (base + 1 < n) offs[base + 1] = ex + p1;
    if (base + 2 < n) offs[base + 2] = ex + p2;
    if (base + 3 < n) offs[base + 3] = ex + p3;
    if (tid == 255) blockSums[b] = sd[255];
}

__global__ __launch_bounds__(256) void scan2_kernel(
    const int* __restrict__ blockSums, int* __restrict__ blockOffs, int nb) {
    __shared__ int sd[256];
    int tid = threadIdx.x;
    int v = tid < nb ? blockSums[tid] : 0;
    sd[tid] = v;
    __syncthreads();
    #pragma unroll
    for (int off = 1; off < 256; off <<= 1) {
        int t = tid >= off ? sd[tid - off] : 0;
        __syncthreads();
        sd[tid] += t;
        __syncthreads();
    }
    blockOffs[tid] = sd[tid] - v;
}

// ---------------- fused scatter, zero atomics; blockOffs folded in
__global__ __launch_bounds__(256) void scatter_fused_kernel(
    const int* __restrict__ src_id, const int* __restrict__ tgt_id,
    const float* __restrict__ score_i, const float* __restrict__ score_j,
    const int* __restrict__ offs, const int* __restrict__ blockOffs,
    const int* __restrict__ rank, uint2* __restrict__ pairs, int E) {
    int e = blockIdx.x * blockDim.x + threadIdx.x;
    if (e >= E) return;
    int s = src_id[e], t = tgt_id[e];
    float x = score_i[s] + score_j[t];
    x = x > 0.f ? x : LEAKY * x;
    x = fminf(30.f, fmaxf(-30.f, x));
    float ex = expf(x);
    int p = offs[s] + blockOffs[s >> 10] + rank[e];
    pairs[p] = make_uint2((unsigned int)t, __float_as_uint(ex));
}

// ---------------- aggregate: wave per node, 4 edges in flight, inline denom, fused ELU
__global__ __launch_bounds__(256) void agg_kernel(
    const uint2* __restrict__ pairs, const int* __restrict__ offs,
    const int* __restrict__ blockOffs, const unsigned short* __restrict__ hjb,
    float* __restrict__ out, int N, int E) {
    int node = (int)((blockIdx.x * (long long)blockDim.x + threadIdx.x) >> 6);
    if (node >= N) return;
    int lane = threadIdx.x & 63;
    int q  = lane >> 4;
    int cl = lane & 15;
    int beg = offs[node] + blockOffs[node >> 10];
    int end = (node + 1 < N) ? offs[node + 1] + blockOffs[(node + 1) >> 10] : E;
    int deg = end - beg;
    float den = 0.f;
    float acc[8];
    #pragma unroll
    for (int i = 0; i < 8; ++i) acc[i] = 0.f;

    int iters = (deg + 3) >> 2;
    for (int it = 0; it < iters; ++it) {
        int e = q + 4 * it;
        bool valid = e < deg;
        int idx = beg + (valid ? e : 0);
        uint2 tw = pairs[idx];
        int t = (int)tw.x;
        float wgt = valid ? __uint_as_float(tw.y) : 0.f;
        den += wgt;
        uint4 u = *(const uint4*)(hjb + (size_t)t * OUT_DIM + cl * 8);
        acc[0] += bf2f(u.x & 0xffffu) * wgt;
        acc[1] += bf2f(u.x >> 16) * wgt;
        acc[2] += bf2f(u.y & 0xffffu) * wgt;
        acc[3] += bf2f(u.y >> 16) * wgt;
        acc[4] += bf2f(u.z & 0xffffu) * wgt;
        acc[5] += bf2f(u.z >> 16) * wgt;
        acc[6] += bf2f(u.w & 0xffffu) * wgt;
        acc[7] += bf2f(u.w >> 16) * wgt;
    }
    den += __shfl_xor(den, 16);
    den += __shfl_xor(den, 32);
    float inv = 1.f / (den + 1e-8f);
    #pragma unroll
    for (int i = 0; i < 8; ++i) {
        acc[i] += __shfl_xor(acc[i], 16);
        acc[i] += __shfl_xor(acc[i], 32);
        acc[i] *= inv;
        acc[i] = acc[i] > 0.f ? acc[i] : expm1f(acc[i]);
    }
    if (lane < 16) {
        float4 v0 = make_float4(acc[0], acc[1], acc[2], acc[3]);
        float4 v1 = make_float4(acc[4], acc[5], acc[6], acc[7]);
        *(float4*)(out + (size_t)node * OUT_DIM + cl * 8) = v0;
        *(float4*)(out + (size_t)node * OUT_DIM + cl * 8 + 4) = v1;
    }
}

// ---------------- fallback path (atomic scatter) if ws too small
__global__ __launch_bounds__(256) void edge_pass1_kernel(
    const int* __restrict__ src_id, const int* __restrict__ tgt_id,
    const float* __restrict__ score_i, const float* __restrict__ score_j,
    float* __restrict__ exp_e, float* __restrict__ denom, int E) {
    int e = blockIdx.x * blockDim.x + threadIdx.x;
    if (e >= E) return;
    int s = src_id[e], t = tgt_id[e];
    float x = score_i[s] + score_j[t];
    x = x > 0.f ? x : LEAKY * x;
    x = fminf(30.f, fmaxf(-30.f, x));
    float ex = expf(x);
    exp_e[e] = ex;
    atomicAdd(&denom[s], ex);
}

__global__ __launch_bounds__(256) void edge_pass2_kernel(
    const int* __restrict__ src_id, const int* __restrict__ tgt_id,
    const unsigned short* __restrict__ hjb, const float* __restrict__ exp_e,
    const float* __restrict__ denom, float* __restrict__ out, int E) {
    int idx = blockIdx.x * blockDim.x + threadIdx.x;
    int e = idx >> 6;
    if (e >= E) return;
    int lane = idx & 63;
    int s = src_id[e], t = tgt_id[e];
    float alpha = exp_e[e] / (denom[s] + 1e-8f);
    unsigned int u = *(const unsigned int*)(hjb + (size_t)t * OUT_DIM + lane * 2);
    atomicAdd(out + (size_t)s * OUT_DIM + lane * 2 + 0, bf2f(u & 0xffffu) * alpha);
    atomicAdd(out + (size_t)s * OUT_DIM + lane * 2 + 1, bf2f(u >> 16) * alpha);
}

__global__ __launch_bounds__(256) void elu_kernel(float* __restrict__ out, int n4) {
    int i = blockIdx.x * blockDim.x + threadIdx.x;
    if (i >= n4) return;
    float4 v = ((float4*)out)[i];
    v.x = v.x > 0.f ? v.x : expm1f(v.x);
    v.y = v.y > 0.f ? v.y : expm1f(v.y);
    v.z = v.z > 0.f ? v.z : expm1f(v.z);
    v.w = v.w > 0.f ? v.w : expm1f(v.w);
    ((float4*)out)[i] = v;
}

extern "C" void kernel_launch(void* const* d_in, const int* in_sizes, int n_in,
                              void* d_out, int out_size, void* d_ws, size_t ws_size,
                              hipStream_t stream) {
    const float* src   = (const float*)d_in[0];
    const float* tgt   = (const float*)d_in[1];
    const float* W_src = (const float*)d_in[2];
    const float* W_tgt = (const float*)d_in[3];
    const float* a     = (const float*)d_in[4];
    const int*   edge  = (const int*)d_in[5];

    int N_src = in_sizes[0] / IN_DIM;
    int N_tgt = in_sizes[1] / IN_DIM;
    int E     = in_sizes[5] / 2;
    const int* src_id = edge;
    const int* tgt_id = edge + E;

    float* out = (float*)d_out;

    char* ws = (char*)d_ws;
    size_t off = 0;
    auto alloc = [&](size_t bytes) {
        void* p = ws + off;
        off += (bytes + 255) & ~(size_t)255;
        return p;
    };

    unsigned short* hjb  = (unsigned short*)alloc((size_t)N_tgt * OUT_DIM * 2);
    float* score_i = (float*)alloc((size_t)N_src * 4);
    float* score_j = (float*)alloc((size_t)N_tgt * 4);
    float* wcomb   = (float*)alloc(256 * 4);
    unsigned short* Wswz = (unsigned short*)alloc(4096 * 8 * 2);
    int*   counts    = (int*)alloc(((size_t)N_src + 3) / 4 * 16);  // int4-aligned
    int*   offs      = (int*)alloc((size_t)(N_src + 1) * 4);
    int*   blockSums = (int*)alloc(256 * 4);
    int*   blockOffs = (int*)alloc(256 * 4);
    float* denom     = (float*)alloc((size_t)N_src * 4);   // fallback only
    float* exp_e     = (float*)alloc((size_t)E * 4);       // fallback only
    size_t fb_need = off;
    int*   rank      = (int*)alloc((size_t)E * 4);
    uint2* pairs     = (uint2*)alloc((size_t)E * 8);
    size_t csr_need = off;
    (void)fb_need;

    bool use_csr = (ws_size >= csr_need);

    int n4 = (N_src + 3) / 4;                 // count of int4s to zero
    int zblocks = (n4 + 255) / 256;
    prep_kernel<<<17 + zblocks, 256, 0, stream>>>(
        W_src, W_tgt, a, wcomb, Wswz, (int4*)counts, n4);

    if (use_csr) {
        int gemvBlocks = (N_src + 31) / 32;
        int histBlocks = (E + 255) / 256;
        int half = gemvBlocks > histBlocks ? gemvBlocks : histBlocks;
        gemv_hist_kernel<<<2 * half, 256, 0, stream>>>(
            src, wcomb, score_i, N_src, src_id, counts, rank, E);
        gemm_mfma_kernel<<<(N_tgt + 31) / 32, 128, 0, stream>>>(
            tgt, Wswz, a + OUT_DIM, hjb, score_j, N_tgt);
        int nb = (N_src + 1023) / 1024;
        scan1_kernel<<<nb, 256, 0, stream>>>(counts, offs, blockSums, N_src);
        scan2_kernel<<<1, 256, 0, stream>>>(blockSums, blockOffs, nb);
        scatter_fused_kernel<<<(E + 255) / 256, 256, 0, stream>>>(
            src_id, tgt_id, score_i, score_j, offs, blockOffs, rank, pairs, E);
        agg_kernel<<<(N_src + 3) / 4, 256, 0, stream>>>(
            pairs, offs, blockOffs, hjb, out, N_src, E);
    } else {
        int gemvBlocks = (N_src + 31) / 32;
        gemv_hist_kernel<<<2 * gemvBlocks, 256, 0, stream>>>(
            src, wcomb, score_i, N_src, src_id, counts, rank, 0);
        gemm_mfma_kernel<<<(N_tgt + 31) / 32, 128, 0, stream>>>(
            tgt, Wswz, a + OUT_DIM, hjb, score_j, N_tgt);
        hipMemsetAsync(out, 0, (size_t)N_src * OUT_DIM * sizeof(float), stream);
        hipMemsetAsync(denom, 0, (size_t)N_src * sizeof(float), stream);
        edge_pass1_kernel<<<(E + 255) / 256, 256, 0, stream>>>(
            src_id, tgt_id, score_i, score_j, exp_e, denom, E);
        edge_pass2_kernel<<<(int)(((long long)E * 64 + 255) / 256), 256, 0, stream>>>(
            src_id, tgt_id, hjb, exp_e, denom, out, E);
        elu_kernel<<<(N_src * OUT_DIM / 4 + 255) / 256, 256, 0, stream>>>(
            out, N_src * OUT_DIM / 4);
    }
}

// Round 13
// 142.101 us; speedup vs baseline: 1.3617x; 1.0629x over previous
//
#include <hip/hip_runtime.h>
#include <hip/hip_bf16.h>
#include <math.h>

#define IN_DIM 256
#define OUT_DIM 128
#define LEAKY 0.2f

typedef __attribute__((ext_vector_type(8))) short bf16x8;
typedef __attribute__((ext_vector_type(4))) float f32x4;

__device__ __forceinline__ unsigned short f2bf(float f) {
    union { float f; unsigned int u; } v; v.f = f;
    unsigned int r = v.u + 0x7FFFu + ((v.u >> 16) & 1u);
    return (unsigned short)(r >> 16);
}
__device__ __forceinline__ float bf2f(unsigned int hi16) {
    union { unsigned int u; float f; } v; v.u = hi16 << 16;
    return v.f;
}

// ---------------- prep: blocks 0..15 = wswz (W_tgt -> bf16 fragment-major),
//                  block 16 = wcomb = W_src @ a[0:128], blocks 17.. zero counts
__global__ __launch_bounds__(256) void prep_kernel(
    const float* __restrict__ W_src, const float* __restrict__ W_tgt,
    const float* __restrict__ a, float* __restrict__ wcomb,
    unsigned short* __restrict__ Wswz, int4* __restrict__ counts4, int n4) {
    if (blockIdx.x >= 17) {
        int i = (blockIdx.x - 17) * 256 + threadIdx.x;
        if (i < n4) counts4[i] = make_int4(0, 0, 0, 0);
        return;
    }
    if (blockIdx.x == 16) {
        int i = threadIdx.x;
        float s = 0.f;
        #pragma unroll 4
        for (int k = 0; k < OUT_DIM; ++k) s += W_src[i * OUT_DIM + k] * a[k];
        wcomb[i] = s;
        return;
    }
    int idx = blockIdx.x * 256 + threadIdx.x;   // 0..4095
    int l  = idx & 63;
    int fj = (idx >> 6) & 7;
    int kc = idx >> 9;
    int col = fj * 16 + (l & 15);
    int kb  = kc * 32 + (l >> 4) * 8;
    unsigned int u[4];
    #pragma unroll
    for (int p = 0; p < 4; ++p) {
        unsigned short e0 = f2bf(W_tgt[(size_t)(kb + 2 * p + 0) * OUT_DIM + col]);
        unsigned short e1 = f2bf(W_tgt[(size_t)(kb + 2 * p + 1) * OUT_DIM + col]);
        u[p] = (unsigned int)e0 | ((unsigned int)e1 << 16);
    }
    *(uint4*)(Wswz + (size_t)idx * 8) = make_uint4(u[0], u[1], u[2], u[3]);
}

// ---------------- PHASE 1 (fused): gemm + gemv + hist, interleaved block types.
// Pattern of 9 blocks: r in {0,4} -> gemm (2/9), r in {1,3,5,7} -> gemv (4/9),
// r in {2,6,8} -> hist (3/9). Matches block ratio 1563:3125:2344 = 2:4:3.
// gemm branch = round-8/11-proven 64-row / 256-thr / 32KB body, bit-identical.
__global__ __launch_bounds__(256) void phase1_kernel(
    const float* __restrict__ A, const unsigned short* __restrict__ Wswz,
    const float* __restrict__ a_hi, unsigned short* __restrict__ Hb,
    float* __restrict__ score_j, int Mt, int G,
    const float* __restrict__ X, const float* __restrict__ w,
    float* __restrict__ score_i, int Ms, int V,
    const int* __restrict__ src_id, int* __restrict__ counts,
    int* __restrict__ rank, int E, int H) {
    __shared__ unsigned short As[64 * 256];  // 32 KB (used by gemm branch only)
    int b = blockIdx.x;
    int g = b / 9;
    int r = b - g * 9;
    int tid = threadIdx.x;

    if (r == 2 || r == 6 || r == 8) {
        // ---- hist branch
        int hb = g * 3 + (r == 6 ? 1 : (r == 8 ? 2 : 0));
        if (hb >= H) return;
        int e = hb * 256 + tid;
        if (e < E) rank[e] = atomicAdd(&counts[src_id[e]], 1);
        return;
    }
    if (r != 0 && r != 4) {
        // ---- gemv branch: 8 lanes/row, 8 x float4/lane, 32 rows/block
        int vb = g * 4 + (r == 3 ? 1 : (r == 5 ? 2 : (r == 7 ? 3 : 0)));
        if (vb >= V) return;
        int row = vb * 32 + (tid >> 3);
        if (row >= Ms) return;
        int k = tid & 7;
        const float4* R = (const float4*)(X + (size_t)row * IN_DIM);
        const float4* W4 = (const float4*)w;
        float s = 0.f;
        #pragma unroll
        for (int c = 0; c < 8; ++c) {
            float4 x = R[k + 8 * c];
            float4 wv = W4[k + 8 * c];
            s += x.x * wv.x + x.y * wv.y + x.z * wv.z + x.w * wv.w;
        }
        s += __shfl_xor(s, 1);
        s += __shfl_xor(s, 2);
        s += __shfl_xor(s, 4);
        if (k == 0) score_i[row] = s;
        return;
    }
    // ---- gemm branch (block-uniform; __syncthreads is safe)
    int gb = g * 2 + (r == 4 ? 1 : 0);
    if (gb >= G) return;
    int w4 = tid >> 6;
    int l = tid & 63;
    int bm = gb * 64;

    int srow = tid >> 4;          // 0..15
    int kcol = (tid & 15) * 4;    // 0..60

    float aw[8];
    #pragma unroll
    for (int j = 0; j < 8; ++j) aw[j] = a_hi[j * 16 + (l & 15)];

    f32x4 acc[8];
    f32x4 zero = {0.f, 0.f, 0.f, 0.f};
    #pragma unroll
    for (int j = 0; j < 8; ++j) acc[j] = zero;

    float4 pre[16];
    #pragma unroll
    for (int p = 0; p < 4; ++p) {
        int grow = bm + srow + p * 16;
        const float* rp = A + (size_t)(grow < Mt ? grow : Mt - 1) * IN_DIM;
        bool ok = grow < Mt;
        #pragma unroll
        for (int c = 0; c < 4; ++c) {
            float4 v = *(const float4*)(rp + c * 64 + kcol);
            pre[p * 4 + c] = ok ? v : make_float4(0.f, 0.f, 0.f, 0.f);
        }
    }
    #pragma unroll
    for (int p = 0; p < 4; ++p) {
        int row = srow + p * 16;
        #pragma unroll
        for (int c = 0; c < 4; ++c) {
            float4 v = pre[p * 4 + c];
            unsigned int b0 = (unsigned int)f2bf(v.x) | ((unsigned int)f2bf(v.y) << 16);
            unsigned int b1 = (unsigned int)f2bf(v.z) | ((unsigned int)f2bf(v.w) << 16);
            unsigned int byteoff =
                (unsigned int)(row * 512 + (c * 64 + kcol) * 2) ^ ((row & 7) << 4);
            *(uint2*)((char*)As + byteoff) = make_uint2(b0, b1);
        }
    }
    __syncthreads();

    #pragma unroll
    for (int kc = 0; kc < 8; ++kc) {
        int row = w4 * 16 + (l & 15);
        unsigned int byteoff =
            (unsigned int)(row * 512 + kc * 64 + (l >> 4) * 16) ^ ((row & 7) << 4);
        bf16x8 af = *(const bf16x8*)((const char*)As + byteoff);
        #pragma unroll
        for (int j = 0; j < 8; ++j) {
            bf16x8 bfj = *(const bf16x8*)(Wswz + ((size_t)(kc * 8 + j) * 64 + l) * 8);
            acc[j] = __builtin_amdgcn_mfma_f32_16x16x32_bf16(af, bfj, acc[j], 0, 0, 0);
        }
    }
    #pragma unroll
    for (int rr = 0; rr < 4; ++rr) {
        int row = bm + w4 * 16 + (l >> 4) * 4 + rr;
        if (row < Mt) {
            float s = 0.f;
            #pragma unroll
            for (int j = 0; j < 8; ++j) {
                float v = acc[j][rr];
                Hb[(size_t)row * OUT_DIM + j * 16 + (l & 15)] = f2bf(v);
                s += v * aw[j];
            }
            s += __shfl_xor(s, 1); s += __shfl_xor(s, 2);
            s += __shfl_xor(s, 4); s += __shfl_xor(s, 8);
            if ((l & 15) == 0) score_j[row] = s;
        }
    }
}

// ---------------- 2-level exclusive scan (partial offs + block offsets)
__global__ __launch_bounds__(256) void scan1_kernel(
    const int* __restrict__ counts, int* __restrict__ offs,
    int* __restrict__ blockSums, int n) {
    __shared__ int sd[256];
    int b = blockIdx.x, tid = threadIdx.x;
    int base = b * 1024 + tid * 4;
    int v0 = base + 0 < n ? counts[base + 0] : 0;
    int v1 = base + 1 < n ? counts[base + 1] : 0;
    int v2 = base + 2 < n ? counts[base + 2] : 0;
    int v3 = base + 3 < n ? counts[base + 3] : 0;
    int p1 = v0, p2 = v0 + v1, p3 = v0 + v1 + v2;
    int tsum = p3 + v3;
    sd[tid] = tsum;
    __syncthreads();
    #pragma unroll
    for (int off = 1; off < 256; off <<= 1) {
        int t = tid >= off ? sd[tid - off] : 0;
        __syncthreads();
        sd[tid] += t;
        __syncthreads();
    }
    int ex = sd[tid] - tsum;
    if (base + 0 < n) offs[base + 0] = ex;
    if (base + 1 < n) offs[base + 1] = ex + p1;
    if (base + 2 < n) offs[base + 2] = ex + p2;
    if (base + 3 < n) offs[base + 3] = ex + p3;
    if (tid == 255) blockSums[b] = sd[255];
}

__global__ __launch_bounds__(256) void scan2_kernel(
    const int* __restrict__ blockSums, int* __restrict__ blockOffs, int nb) {
    __shared__ int sd[256];
    int tid = threadIdx.x;
    int v = tid < nb ? blockSums[tid] : 0;
    sd[tid] = v;
    __syncthreads();
    #pragma unroll
    for (int off = 1; off < 256; off <<= 1) {
        int t = tid >= off ? sd[tid - off] : 0;
        __syncthreads();
        sd[tid] += t;
        __syncthreads();
    }
    blockOffs[tid] = sd[tid] - v;
}

// ---------------- fused scatter, zero atomics; blockOffs folded in
__global__ __launch_bounds__(256) void scatter_fused_kernel(
    const int* __restrict__ src_id, const int* __restrict__ tgt_id,
    const float* __restrict__ score_i, const float* __restrict__ score_j,
    const int* __restrict__ offs, const int* __restrict__ blockOffs,
    const int* __restrict__ rank, uint2* __restrict__ pairs, int E) {
    int e = blockIdx.x * blockDim.x + threadIdx.x;
    if (e >= E) return;
    int s = src_id[e], t = tgt_id[e];
    float x = score_i[s] + score_j[t];
    x = x > 0.f ? x : LEAKY * x;
    x = fminf(30.f, fmaxf(-30.f, x));
    float ex = expf(x);
    int p = offs[s] + blockOffs[s >> 10] + rank[e];
    pairs[p] = make_uint2((unsigned int)t, __float_as_uint(ex));
}

// ---------------- aggregate: wave per node, 4 edges in flight, inline denom, fused ELU
__global__ __launch_bounds__(256) void agg_kernel(
    const uint2* __restrict__ pairs, const int* __restrict__ offs,
    const int* __restrict__ blockOffs, const unsigned short* __restrict__ hjb,
    float* __restrict__ out, int N, int E) {
    int node = (int)((blockIdx.x * (long long)blockDim.x + threadIdx.x) >> 6);
    if (node >= N) return;
    int lane = threadIdx.x & 63;
    int q  = lane >> 4;
    int cl = lane & 15;
    int beg = offs[node] + blockOffs[node >> 10];
    int end = (node + 1 < N) ? offs[node + 1] + blockOffs[(node + 1) >> 10] : E;
    int deg = end - beg;
    float den = 0.f;
    float acc[8];
    #pragma unroll
    for (int i = 0; i < 8; ++i) acc[i] = 0.f;

    int iters = (deg + 3) >> 2;
    for (int it = 0; it < iters; ++it) {
        int e = q + 4 * it;
        bool valid = e < deg;
        int idx = beg + (valid ? e : 0);
        uint2 tw = pairs[idx];
        int t = (int)tw.x;
        float wgt = valid ? __uint_as_float(tw.y) : 0.f;
        den += wgt;
        uint4 u = *(const uint4*)(hjb + (size_t)t * OUT_DIM + cl * 8);
        acc[0] += bf2f(u.x & 0xffffu) * wgt;
        acc[1] += bf2f(u.x >> 16) * wgt;
        acc[2] += bf2f(u.y & 0xffffu) * wgt;
        acc[3] += bf2f(u.y >> 16) * wgt;
        acc[4] += bf2f(u.z & 0xffffu) * wgt;
        acc[5] += bf2f(u.z >> 16) * wgt;
        acc[6] += bf2f(u.w & 0xffffu) * wgt;
        acc[7] += bf2f(u.w >> 16) * wgt;
    }
    den += __shfl_xor(den, 16);
    den += __shfl_xor(den, 32);
    float inv = 1.f / (den + 1e-8f);
    #pragma unroll
    for (int i = 0; i < 8; ++i) {
        acc[i] += __shfl_xor(acc[i], 16);
        acc[i] += __shfl_xor(acc[i], 32);
        acc[i] *= inv;
        acc[i] = acc[i] > 0.f ? acc[i] : expm1f(acc[i]);
    }
    if (lane < 16) {
        float4 v0 = make_float4(acc[0], acc[1], acc[2], acc[3]);
        float4 v1 = make_float4(acc[4], acc[5], acc[6], acc[7]);
        *(float4*)(out + (size_t)node * OUT_DIM + cl * 8) = v0;
        *(float4*)(out + (size_t)node * OUT_DIM + cl * 8 + 4) = v1;
    }
}

// ---------------- fallback path (atomic scatter) if ws too small
__global__ __launch_bounds__(256) void edge_pass1_kernel(
    const int* __restrict__ src_id, const int* __restrict__ tgt_id,
    const float* __restrict__ score_i, const float* __restrict__ score_j,
    float* __restrict__ exp_e, float* __restrict__ denom, int E) {
    int e = blockIdx.x * blockDim.x + threadIdx.x;
    if (e >= E) return;
    int s = src_id[e], t = tgt_id[e];
    float x = score_i[s] + score_j[t];
    x = x > 0.f ? x : LEAKY * x;
    x = fminf(30.f, fmaxf(-30.f, x));
    float ex = expf(x);
    exp_e[e] = ex;
    atomicAdd(&denom[s], ex);
}

__global__ __launch_bounds__(256) void edge_pass2_kernel(
    const int* __restrict__ src_id, const int* __restrict__ tgt_id,
    const unsigned short* __restrict__ hjb, const float* __restrict__ exp_e,
    const float* __restrict__ denom, float* __restrict__ out, int E) {
    int idx = blockIdx.x * blockDim.x + threadIdx.x;
    int e = idx >> 6;
    if (e >= E) return;
    int lane = idx & 63;
    int s = src_id[e], t = tgt_id[e];
    float alpha = exp_e[e] / (denom[s] + 1e-8f);
    unsigned int u = *(const unsigned int*)(hjb + (size_t)t * OUT_DIM + lane * 2);
    atomicAdd(out + (size_t)s * OUT_DIM + lane * 2 + 0, bf2f(u & 0xffffu) * alpha);
    atomicAdd(out + (size_t)s * OUT_DIM + lane * 2 + 1, bf2f(u >> 16) * alpha);
}

__global__ __launch_bounds__(256) void elu_kernel(float* __restrict__ out, int n4) {
    int i = blockIdx.x * blockDim.x + threadIdx.x;
    if (i >= n4) return;
    float4 v = ((float4*)out)[i];
    v.x = v.x > 0.f ? v.x : expm1f(v.x);
    v.y = v.y > 0.f ? v.y : expm1f(v.y);
    v.z = v.z > 0.f ? v.z : expm1f(v.z);
    v.w = v.w > 0.f ? v.w : expm1f(v.w);
    ((float4*)out)[i] = v;
}

extern "C" void kernel_launch(void* const* d_in, const int* in_sizes, int n_in,
                              void* d_out, int out_size, void* d_ws, size_t ws_size,
                              hipStream_t stream) {
    const float* src   = (const float*)d_in[0];
    const float* tgt   = (const float*)d_in[1];
    const float* W_src = (const float*)d_in[2];
    const float* W_tgt = (const float*)d_in[3];
    const float* a     = (const float*)d_in[4];
    const int*   edge  = (const int*)d_in[5];

    int N_src = in_sizes[0] / IN_DIM;
    int N_tgt = in_sizes[1] / IN_DIM;
    int E     = in_sizes[5] / 2;
    const int* src_id = edge;
    const int* tgt_id = edge + E;

    float* out = (float*)d_out;

    char* ws = (char*)d_ws;
    size_t off = 0;
    auto alloc = [&](size_t bytes) {
        void* p = ws + off;
        off += (bytes + 255) & ~(size_t)255;
        return p;
    };

    unsigned short* hjb  = (unsigned short*)alloc((size_t)N_tgt * OUT_DIM * 2);
    float* score_i = (float*)alloc((size_t)N_src * 4);
    float* score_j = (float*)alloc((size_t)N_tgt * 4);
    float* wcomb   = (float*)alloc(256 * 4);
    unsigned short* Wswz = (unsigned short*)alloc(4096 * 8 * 2);
    int*   counts    = (int*)alloc(((size_t)N_src + 3) / 4 * 16);  // int4-aligned
    int*   offs      = (int*)alloc((size_t)(N_src + 1) * 4);
    int*   blockSums = (int*)alloc(256 * 4);
    int*   blockOffs = (int*)alloc(256 * 4);
    float* denom     = (float*)alloc((size_t)N_src * 4);   // fallback only
    float* exp_e     = (float*)alloc((size_t)E * 4);       // fallback only
    size_t fb_need = off;
    int*   rank      = (int*)alloc((size_t)E * 4);
    uint2* pairs     = (uint2*)alloc((size_t)E * 8);
    size_t csr_need = off;
    (void)fb_need;

    bool use_csr = (ws_size >= csr_need);

    int n4 = (N_src + 3) / 4;                 // count of int4s to zero
    int zblocks = (n4 + 255) / 256;
    prep_kernel<<<17 + zblocks, 256, 0, stream>>>(
        W_src, W_tgt, a, wcomb, Wswz, (int4*)counts, n4);

    // fused phase 1: gemm + gemv + hist (pattern of 9: 2 gemm, 4 gemv, 3 hist)
    int G = (N_tgt + 63) / 64;
    int V = (N_src + 31) / 32;
    int H = (E + 255) / 256;
    int gmax = (G + 1) / 2;
    int vmax = (V + 3) / 4;
    int hmax = (H + 2) / 3;
    int groups = gmax > vmax ? gmax : vmax;
    if (hmax > groups) groups = hmax;
    phase1_kernel<<<groups * 9, 256, 0, stream>>>(
        tgt, Wswz, a + OUT_DIM, hjb, score_j, N_tgt, G,
        src, wcomb, score_i, N_src, V,
        src_id, counts, rank, E, H);

    if (use_csr) {
        int nb = (N_src + 1023) / 1024;
        scan1_kernel<<<nb, 256, 0, stream>>>(counts, offs, blockSums, N_src);
        scan2_kernel<<<1, 256, 0, stream>>>(blockSums, blockOffs, nb);
        scatter_fused_kernel<<<(E + 255) / 256, 256, 0, stream>>>(
            src_id, tgt_id, score_i, score_j, offs, blockOffs, rank, pairs, E);
        agg_kernel<<<(N_src + 3) / 4, 256, 0, stream>>>(
            pairs, offs, blockOffs, hjb, out, N_src, E);
    } else {
        hipMemsetAsync(out, 0, (size_t)N_src * OUT_DIM * sizeof(float), stream);
        hipMemsetAsync(denom, 0, (size_t)N_src * sizeof(float), stream);
        edge_pass1_kernel<<<(E + 255) / 256, 256, 0, stream>>>(
            src_id, tgt_id, score_i, score_j, exp_e, denom, E);
        edge_pass2_kernel<<<(int)(((long long)E * 64 + 255) / 256), 256, 0, stream>>>(
            src_id, tgt_id, hjb, exp_e, denom, out, E);
        elu_kernel<<<(N_src * OUT_DIM / 4 + 255) / 256, 256, 0, stream>>>(
            out, N_src * OUT_DIM / 4);
    }
}